// Round 11
// baseline (2588.378 us; speedup 1.0000x reference)
//
#include <hip/hip_runtime.h>
#include <hip/hip_bf16.h>

#define NNODE 8192
#define DEG   32
#define DIN   256
#define EDIM  64
#define KC    576            // 2*DIN + EDIM
#define DD    512            // internal width D
#define MEDGE (NNODE*DEG)
#define EAWP  516            // 512 + 4 f32 pad (k1 LDS)

typedef __attribute__((ext_vector_type(8))) short short8;
typedef __attribute__((ext_vector_type(4))) short short4v;
typedef __attribute__((ext_vector_type(4))) float floatx4;
typedef __attribute__((ext_vector_type(4))) unsigned int uint4v;
typedef unsigned int u32;

__device__ __forceinline__ ushort f2bf(float f) {
  union { float f; unsigned int i; } v; v.f = f;
  return (ushort)((v.i + 0x7fffu + ((v.i >> 16) & 1u)) >> 16);
}
__device__ __forceinline__ u32 pk2(float a, float b) {
  return (u32)f2bf(a) | ((u32)f2bf(b) << 16);
}
__device__ __forceinline__ float gelu_f(float z) {
  return 0.5f * z * (1.0f + erff(z * 0.70710678118654752f));
}
__device__ __forceinline__ floatx4 zero4() { floatx4 v = {0.f, 0.f, 0.f, 0.f}; return v; }

__device__ __forceinline__ short8 ld_cvt8(const float* __restrict__ p) {
  floatx4 a = *(const floatx4*)(p);
  floatx4 b = *(const floatx4*)(p + 4);
  short8 r;
  r[0] = (short)f2bf(a[0]); r[1] = (short)f2bf(a[1]);
  r[2] = (short)f2bf(a[2]); r[3] = (short)f2bf(a[3]);
  r[4] = (short)f2bf(b[0]); r[5] = (short)f2bf(b[1]);
  r[6] = (short)f2bf(b[2]); r[7] = (short)f2bf(b[3]);
  return r;
}

#define MFMA16(a, b, c) __builtin_amdgcn_mfma_f32_16x16x32_bf16((a), (b), (c), 0, 0, 0)

// bijective XCD swizzle (m204): contiguous wgid chunks per XCD
__device__ __forceinline__ int xswz(int orig, int nwg) {
  const int q = nwg >> 3, r = nwg & 7;
  const int xcd = orig & 7, idx = orig >> 3;
  return (xcd < r ? xcd * (q + 1) : r * (q + 1) + (xcd - r) * q) + idx;
}

// D-layout -> A/B-frag-layout in-register transform (verified r2-r10).
__device__ __forceinline__ u32 bpsel(int a, u32 v0, u32 v1, bool hi) {
  u32 x0 = (u32)__builtin_amdgcn_ds_bpermute(a, (int)v0);
  u32 x1 = (u32)__builtin_amdgcn_ds_bpermute(a, (int)v1);
  return hi ? x1 : x0;
}
__device__ __forceinline__ short8 frag4(int a0, int a1, bool hi,
                                        u32 t00, u32 t01, u32 t10, u32 t11) {
  uint4v r;
  r[0] = bpsel(a0, t00, t10, hi);
  r[1] = bpsel(a0, t01, t11, hi);
  r[2] = bpsel(a1, t00, t10, hi);
  r[3] = bpsel(a1, t01, t11, hi);
  union { uint4v u; short8 s; } c; c.u = r; return c.s;
}

// async global -> LDS, 16 bytes per lane (wave-uniform LDS base + lane*16)
__device__ __forceinline__ void gl_lds16(const void* g, void* l) {
  __builtin_amdgcn_global_load_lds(
      (const __attribute__((address_space(1))) void*)g,
      (__attribute__((address_space(3))) void*)l,
      16, 0, 0);
}

// stage a [128 rows][64 k] bf16 tile (16 KB); gbase at (row0,k0); pitch in elems
__device__ __forceinline__ void stage_tile(const ushort* gbase, ushort* sdst,
                                           int tid, int pitch) {
  #pragma unroll
  for (int j = 0; j < 4; ++j) {
    const int off = (j * 256 + tid) * 16;   // byte offset in tile
    const int row = off >> 7;               // /128 (row = 128 B)
    const int kb  = off & 127;
    const char* g = (const char*)gbase + (size_t)row * (pitch * 2) + kb;
    char* l = (char*)sdst + j * 4096 + (tid >> 6) * 1024;   // wave-uniform
    gl_lds16(g, l);
  }
}

// ============================================================================
// K0 (tiled): P12 = Xb @ [Wc1^T | Wc2^T] (f32 out). grid (64, 8); 128x128 tile.
// ============================================================================
__global__ __launch_bounds__(256) void k0_p12(
    const ushort* __restrict__ xb, const ushort* __restrict__ Wcb,
    float* __restrict__ P12)
{
  __shared__ __align__(16) ushort sA[128 * 64];
  __shared__ __align__(16) ushort sB[128 * 64];

  const int bx   = blockIdx.x;
  const int nt8  = blockIdx.y;
  const int koff = (nt8 >= 4) ? 256 : 0;
  const int tid = threadIdx.x;
  const int w = tid >> 6, l = tid & 63, lr = l & 15, lg = l >> 4;
  const int wm = w >> 1, wn = w & 1;

  floatx4 acc[4][4];
  #pragma unroll
  for (int mt = 0; mt < 4; ++mt)
    #pragma unroll
    for (int nt = 0; nt < 4; ++nt) acc[mt][nt] = zero4();

  const ushort* gA = xb + (size_t)bx * 128 * DIN;
  const ushort* gB = Wcb + (size_t)((nt8 & 3) * 128) * KC + koff;

  for (int ks = 0; ks < 4; ++ks) {
    stage_tile(gA + ks * 64, sA, tid, DIN);
    stage_tile(gB + ks * 64, sB, tid, KC);
    __syncthreads();
    #pragma unroll
    for (int ksub = 0; ksub < 2; ++ksub) {
      short8 a[4], b[4];
      #pragma unroll
      for (int mt = 0; mt < 4; ++mt)
        a[mt] = *(const short8*)(&sA[(wm * 64 + mt * 16 + lr) * 64 + ksub * 32 + lg * 8]);
      #pragma unroll
      for (int nt = 0; nt < 4; ++nt)
        b[nt] = *(const short8*)(&sB[(wn * 64 + nt * 16 + lr) * 64 + ksub * 32 + lg * 8]);
      #pragma unroll
      for (int mt = 0; mt < 4; ++mt)
        #pragma unroll
        for (int nt = 0; nt < 4; ++nt)
          acc[mt][nt] = MFMA16(a[mt], b[nt], acc[mt][nt]);
    }
    __syncthreads();
  }
  const int c0 = nt8 * 128 + wn * 64;
  const int r0 = bx * 128 + wm * 64;
  #pragma unroll
  for (int mt = 0; mt < 4; ++mt)
    #pragma unroll
    for (int nt = 0; nt < 4; ++nt)
      #pragma unroll
      for (int i = 0; i < 4; ++i)
        P12[(size_t)(r0 + mt * 16 + lg * 4 + i) * 1024 + c0 + nt * 16 + lr] = acc[mt][nt][i];
}

// ============================================================================
// K1: ex = gelu(gelu(P1[src] + P2[dst] + ea@Wc3^T + bc)).  (r10 verbatim)
// ============================================================================
__global__ __launch_bounds__(256, 2) void k1_ex(
    const float* __restrict__ ea, const int* __restrict__ e,
    const ushort* __restrict__ Wcb, const float* __restrict__ bc,
    const float* __restrict__ P12,
    ushort* __restrict__ exC, int n0)
{
  __shared__ float sEAW[32 * EAWP];   // [32 edges][512] f32, pad 4
  __shared__ float sP1B[512];         // P1[src] + bc

  const int m0  = (n0 + blockIdx.x * 2) * DEG;
  const int le0 = blockIdx.x * 64;
  const int tid = threadIdx.x;
  const int w = tid >> 6, l = tid & 63, lr = l & 15, lg = l >> 4;

  for (int nn = 0; nn < 2; ++nn) {
    if (tid < 128) {
      const int node = e[m0 + nn * DEG];
      floatx4 a = *(const floatx4*)(P12 + (size_t)node * 1024 + tid * 4);
      floatx4 b = *(const floatx4*)(bc + tid * 4);
      #pragma unroll
      for (int q = 0; q < 4; ++q) a[q] += b[q];
      *(floatx4*)(&sP1B[tid * 4]) = a;
    }
    for (int p = 0; p < 2; ++p) {
      const int cb = w * 128 + p * 64;
      floatx4 acc[2][4];
      #pragma unroll
      for (int et = 0; et < 2; ++et)
        #pragma unroll
        for (int nt = 0; nt < 4; ++nt) acc[et][nt] = zero4();
      #pragma unroll
      for (int s = 0; s < 2; ++s) {
        short8 bfr[4];
        #pragma unroll
        for (int nt = 0; nt < 4; ++nt)
          bfr[nt] = *(const short8*)(Wcb + (size_t)(cb + nt * 16 + lr) * KC + 512 + s * 32 + lg * 8);
        #pragma unroll
        for (int et = 0; et < 2; ++et) {
          short8 af = ld_cvt8(ea + (size_t)(m0 + nn * 32 + et * 16 + lr) * EDIM + s * 32 + lg * 8);
          #pragma unroll
          for (int nt = 0; nt < 4; ++nt)
            acc[et][nt] = MFMA16(af, bfr[nt], acc[et][nt]);
        }
      }
      #pragma unroll
      for (int et = 0; et < 2; ++et)
        #pragma unroll
        for (int nt = 0; nt < 4; ++nt)
          #pragma unroll
          for (int i = 0; i < 4; ++i)
            sEAW[(et * 16 + lg * 4 + i) * EAWP + cb + nt * 16 + lr] = acc[et][nt][i];
    }
    __syncthreads();

    {
      const int eloc = tid >> 3;     // 0..31
      const int k8   = tid & 7;
      const int em   = m0 + nn * 32 + eloc;
      const int dn   = e[MEDGE + em];
      const float* p2r = P12 + (size_t)dn * 1024 + 512;
      const float* erow = &sEAW[eloc * EAWP];
      ushort* exrow = exC + (size_t)(le0 + nn * 32 + eloc) * DD;
      #pragma unroll
      for (int j = 0; j < 8; ++j) {
        const int col = j * 64 + k8 * 8;
        floatx4 q0 = *(const floatx4*)(p2r + col);
        floatx4 q1 = *(const floatx4*)(p2r + col + 4);
        floatx4 e0 = *(const floatx4*)(erow + col);
        floatx4 e1 = *(const floatx4*)(erow + col + 4);
        floatx4 b0 = *(const floatx4*)(&sP1B[col]);
        floatx4 b1 = *(const floatx4*)(&sP1B[col + 4]);
        short8 r;
        #pragma unroll
        for (int q = 0; q < 4; ++q) {
          r[q]     = (short)f2bf(gelu_f(gelu_f(e0[q] + b0[q] + q0[q])));
          r[4 + q] = (short)f2bf(gelu_f(gelu_f(e1[q] + b1[q] + q1[q])));
        }
        *(short8*)(exrow + col) = r;
      }
    }
    __syncthreads();
  }
}

// ============================================================================
// K2a: QKV = exC @ Wi^T. 1-D grid (EC/128 * 12), XCD-swizzled, nt innermost
// so the 12 readers of one exC panel are co-resident on one XCD's L2.
// ============================================================================
__global__ __launch_bounds__(256) void k2a_qkv(
    const ushort* __restrict__ exC, const ushort* __restrict__ Wib,
    const float* __restrict__ bi,
    ushort* __restrict__ Qn, ushort* __restrict__ Kn, ushort* __restrict__ Vt,
    int EC)
{
  __shared__ __align__(16) ushort sA[128 * 64];
  __shared__ __align__(16) ushort sB[128 * 64];

  const int g    = xswz((int)blockIdx.x, (int)gridDim.x);
  const int bx   = g / 12;
  const int nt12 = g % 12;
  const int tid = threadIdx.x;
  const int w = tid >> 6, l = tid & 63, lr = l & 15, lg = l >> 4;
  const int wm = w >> 1, wn = w & 1;

  floatx4 acc[4][4];
  #pragma unroll
  for (int mt = 0; mt < 4; ++mt)
    #pragma unroll
    for (int nt = 0; nt < 4; ++nt) acc[mt][nt] = zero4();

  const ushort* gA = exC + (size_t)bx * 128 * DD;
  const ushort* gB = Wib + (size_t)nt12 * 128 * DD;

  for (int ks = 0; ks < 8; ++ks) {
    stage_tile(gA + ks * 64, sA, tid, DD);
    stage_tile(gB + ks * 64, sB, tid, DD);
    __syncthreads();
    #pragma unroll
    for (int ksub = 0; ksub < 2; ++ksub) {
      short8 a[4], b[4];
      #pragma unroll
      for (int mt = 0; mt < 4; ++mt)
        a[mt] = *(const short8*)(&sA[(wm * 64 + mt * 16 + lr) * 64 + ksub * 32 + lg * 8]);
      #pragma unroll
      for (int nt = 0; nt < 4; ++nt)
        b[nt] = *(const short8*)(&sB[(wn * 64 + nt * 16 + lr) * 64 + ksub * 32 + lg * 8]);
      #pragma unroll
      for (int mt = 0; mt < 4; ++mt)
        #pragma unroll
        for (int nt = 0; nt < 4; ++nt)
          acc[mt][nt] = MFMA16(a[mt], b[nt], acc[mt][nt]);
    }
    __syncthreads();
  }

  const int o0    = nt12 * 128 + wn * 64;
  const int seg   = o0 >> 9;
  const int h     = (o0 >> 6) & 7;
  const int ebase = bx * 128 + wm * 64;

  if (seg < 2) {
    ushort* Dst = (seg == 0 ? Qn : Kn) + (size_t)h * EC * 64;
    #pragma unroll
    for (int nt = 0; nt < 4; ++nt) {
      const int ch = nt * 16 + lr;
      const float bias = bi[o0 + ch];
      #pragma unroll
      for (int mt = 0; mt < 4; ++mt)
        #pragma unroll
        for (int i = 0; i < 4; ++i)
          Dst[(size_t)(ebase + mt * 16 + lg * 4 + i) * 64 + ch] = f2bf(acc[mt][nt][i] + bias);
    }
  } else {
    ushort* Dv = Vt + (size_t)h * 64 * EC;
    #pragma unroll
    for (int nt = 0; nt < 4; ++nt) {
      const int ch = nt * 16 + lr;
      const float bias = bi[o0 + ch];
      #pragma unroll
      for (int mt = 0; mt < 4; ++mt) {
        short4v pk;
        #pragma unroll
        for (int i = 0; i < 4; ++i) pk[i] = (short)f2bf(acc[mt][nt][i] + bias);
        *(short4v*)(&Dv[(size_t)ch * EC + ebase + mt * 16 + lg * 4]) = pk;
      }
    }
  }
}

// ============================================================================
// K2b: attention (r10 verbatim). 512 thr / 8 waves, wave = head; 2 nodes/block.
// ============================================================================
__global__ __launch_bounds__(512, 3) void k2b_attn(
    const ushort* __restrict__ Qn, const ushort* __restrict__ Kn,
    const ushort* __restrict__ Vt,
    ushort* __restrict__ aoC, int EC)
{
  const int le0 = blockIdx.x * 64;
  const int tid = threadIdx.x;
  const int w = tid >> 6, l = tid & 63, lr = l & 15, lg = l >> 4;

  const ushort* Qh = Qn + (size_t)w * EC * 64;
  const ushort* Kh = Kn + (size_t)w * EC * 64;
  const ushort* Vh = Vt + (size_t)w * 64 * EC;

  const int pa0 = ((2 * (lg & 1)) * 16 + lr) * 4;
  const int pa1 = pa0 + 64;
  const bool hi = ((lg >> 1) & 1) != 0;

  #pragma unroll
  for (int n = 0; n < 2; ++n) {
    const int e0 = le0 + n * 32;

    floatx4 sacc[2][2];
    #pragma unroll
    for (int a = 0; a < 2; ++a)
      #pragma unroll
      for (int b = 0; b < 2; ++b) sacc[a][b] = zero4();
    #pragma unroll
    for (int ks2 = 0; ks2 < 2; ++ks2) {
      short8 kfr[2], qfr[2];
      #pragma unroll
      for (int mt = 0; mt < 2; ++mt)
        kfr[mt] = *(const short8*)(Kh + (size_t)(e0 + mt * 16 + lr) * 64 + ks2 * 32 + lg * 8);
      #pragma unroll
      for (int nt = 0; nt < 2; ++nt)
        qfr[nt] = *(const short8*)(Qh + (size_t)(e0 + nt * 16 + lr) * 64 + ks2 * 32 + lg * 8);
      #pragma unroll
      for (int mt = 0; mt < 2; ++mt)
        #pragma unroll
        for (int nt = 0; nt < 2; ++nt)
          sacc[mt][nt] = MFMA16(kfr[mt], qfr[nt], sacc[mt][nt]);
    }

    u32 ppk[2][4];
    #pragma unroll
    for (int nt = 0; nt < 2; ++nt) {
      float s[2][4];
      float mx = -1e30f;
      #pragma unroll
      for (int mt = 0; mt < 2; ++mt)
        #pragma unroll
        for (int i = 0; i < 4; ++i) {
          s[mt][i] = sacc[mt][nt][i] * 0.125f;
          mx = fmaxf(mx, s[mt][i]);
        }
      mx = fmaxf(mx, __shfl_xor(mx, 16));
      mx = fmaxf(mx, __shfl_xor(mx, 32));
      float sm = 0.f;
      #pragma unroll
      for (int mt = 0; mt < 2; ++mt)
        #pragma unroll
        for (int i = 0; i < 4; ++i) { s[mt][i] = expf(s[mt][i] - mx); sm += s[mt][i]; }
      sm += __shfl_xor(sm, 16);
      sm += __shfl_xor(sm, 32);
      const float inv = 1.0f / sm;
      #pragma unroll
      for (int mt = 0; mt < 2; ++mt) {
        ppk[mt][2 * nt + 0] = pk2(s[mt][0] * inv, s[mt][1] * inv);
        ppk[mt][2 * nt + 1] = pk2(s[mt][2] * inv, s[mt][3] * inv);
      }
    }

    short8 paf[2], vbf[4];
    #pragma unroll
    for (int qt = 0; qt < 2; ++qt)
      paf[qt] = frag4(pa0, pa1, hi, ppk[0][2 * qt + 0], ppk[0][2 * qt + 1],
                                    ppk[1][2 * qt + 0], ppk[1][2 * qt + 1]);
    #pragma unroll
    for (int nt = 0; nt < 4; ++nt)
      vbf[nt] = *(const short8*)(Vh + (size_t)(nt * 16 + lr) * EC + e0 + lg * 8);
    #pragma unroll
    for (int qt = 0; qt < 2; ++qt)
      #pragma unroll
      for (int nt = 0; nt < 4; ++nt) {
        floatx4 o = MFMA16(paf[qt], vbf[nt], zero4());
        #pragma unroll
        for (int i = 0; i < 4; ++i)
          aoC[(size_t)(e0 + qt * 16 + lg * 4 + i) * DD + w * 64 + nt * 16 + lr] = f2bf(o[i]);
      }
  }
}

// ============================================================================
// K3: h = gelu(AO @ Wo^T + bo), weighted-mean agg, atomic scatter.
// 1-D grid (EC/128 * 4), XCD-swizzled, nt innermost; gelu in-place on acc;
// reg budget pinned to 128 via launch_bounds -> 16 waves/CU.
// ============================================================================
__global__ __launch_bounds__(256, 4) void k3_out(
    const ushort* __restrict__ aoC, const int* __restrict__ e,
    const ushort* __restrict__ Wob, const float* __restrict__ bo,
    float* __restrict__ out, int n0)
{
  __shared__ __align__(16) ushort sA[128 * 64];
  __shared__ __align__(16) ushort sB[128 * 64];

  const int g   = xswz((int)blockIdx.x, (int)gridDim.x);
  const int bx  = g >> 2;
  const int nt4 = g & 3;
  const int tid = threadIdx.x;
  const int w = tid >> 6, l = tid & 63, lr = l & 15, lg = l >> 4;
  const int wm = w >> 1, wn = w & 1;

  floatx4 acc[4][4];
  #pragma unroll
  for (int mt = 0; mt < 4; ++mt)
    #pragma unroll
    for (int nt = 0; nt < 4; ++nt) acc[mt][nt] = zero4();

  const ushort* gA = aoC + (size_t)bx * 128 * DD;
  const ushort* gB = Wob + (size_t)nt4 * 128 * DD;

  for (int ks = 0; ks < 8; ++ks) {
    stage_tile(gA + ks * 64, sA, tid, DD);
    stage_tile(gB + ks * 64, sB, tid, DD);
    __syncthreads();
    #pragma unroll
    for (int ksub = 0; ksub < 2; ++ksub) {
      short8 a[4], b[4];
      #pragma unroll
      for (int mt = 0; mt < 4; ++mt)
        a[mt] = *(const short8*)(&sA[(wm * 64 + mt * 16 + lr) * 64 + ksub * 32 + lg * 8]);
      #pragma unroll
      for (int nt = 0; nt < 4; ++nt)
        b[nt] = *(const short8*)(&sB[(wn * 64 + nt * 16 + lr) * 64 + ksub * 32 + lg * 8]);
      #pragma unroll
      for (int mt = 0; mt < 4; ++mt)
        #pragma unroll
        for (int nt = 0; nt < 4; ++nt)
          acc[mt][nt] = MFMA16(a[mt], b[nt], acc[mt][nt]);
    }
    __syncthreads();
  }

  const int head = nt4 * 2 + wn;
  // gelu in-place (saves the 64-reg h3 copy)
  #pragma unroll
  for (int nt = 0; nt < 4; ++nt) {
    const float bias = bo[nt4 * 128 + wn * 64 + nt * 16 + lr];
    #pragma unroll
    for (int mt = 0; mt < 4; ++mt)
      #pragma unroll
      for (int i = 0; i < 4; ++i)
        acc[mt][nt][i] = gelu_f(acc[mt][nt][i] + bias);
  }
  float lgA[4][4];
  #pragma unroll
  for (int mt = 0; mt < 4; ++mt)
    #pragma unroll
    for (int i = 0; i < 4; ++i) {
      float tA = acc[mt][2][i] + acc[mt][3][i];
      #pragma unroll
      for (int d2 = 1; d2 < 16; d2 <<= 1) tA += __shfl_xor(tA, d2);
      lgA[mt][i] = tA * (1.0f / 32.0f);
    }
  float eAv[4][4], iA[2];
  #pragma unroll
  for (int n = 0; n < 2; ++n) {
    float mx = -1e30f;
    #pragma unroll
    for (int m2 = 0; m2 < 2; ++m2)
      #pragma unroll
      for (int i = 0; i < 4; ++i) mx = fmaxf(mx, lgA[2 * n + m2][i]);
    mx = fmaxf(mx, __shfl_xor(mx, 16));
    mx = fmaxf(mx, __shfl_xor(mx, 32));
    float sA2 = 0.f;
    #pragma unroll
    for (int m2 = 0; m2 < 2; ++m2)
      #pragma unroll
      for (int i = 0; i < 4; ++i) {
        eAv[2 * n + m2][i] = expf(lgA[2 * n + m2][i] - mx);
        sA2 += eAv[2 * n + m2][i];
      }
    sA2 += __shfl_xor(sA2, 16);
    sA2 += __shfl_xor(sA2, 32);
    iA[n] = 1.0f / sA2;
  }
  const int em0 = (n0 + bx * 4) * DEG + wm * 64;
  #pragma unroll
  for (int mt = 0; mt < 4; ++mt)
    #pragma unroll
    for (int i = 0; i < 4; ++i) {
      const int r  = mt * 16 + lg * 4 + i;
      const int d1 = e[MEDGE + em0 + r];
      float* bp = out + (size_t)d1 * 256 + head * 32;
      const float aA = eAv[mt][i] * iA[mt >> 1];
      atomicAdd(bp + lr,      acc[mt][0][i] * aA);
      atomicAdd(bp + 16 + lr, acc[mt][1][i] * aA);
    }
}

// fp32 -> bf16 pre-convert
__global__ __launch_bounds__(256) void cvt_w(const float* __restrict__ src,
                                             ushort* __restrict__ dst, int n4)
{
  const int i = blockIdx.x * 256 + threadIdx.x;
  if (i < n4) {
    floatx4 v = *(const floatx4*)(src + (size_t)i * 4);
    short4v r;
    #pragma unroll
    for (int j = 0; j < 4; ++j) r[j] = (short)f2bf(v[j]);
    *(short4v*)(dst + (size_t)i * 4) = r;
  }
}

// ws layout: weights bf16 | xb bf16 (4 MB) | P12 f32 (33.5 MB) | chunk buffers
#define WS_WC 0
#define WS_WI (WS_WC + 512*KC)
#define WS_WO (WS_WI + 1536*DD)
#define WB_BYTES   2686976
#define XB_BYTES   4194304
#define P12_BYTES  33554432
#define CHUNK_OFF  (WB_BYTES + XB_BYTES + P12_BYTES)

extern "C" void kernel_launch(void* const* d_in, const int* in_sizes, int n_in,
                              void* d_out, int out_size, void* d_ws, size_t ws_size,
                              hipStream_t stream)
{
  (void)in_sizes; (void)n_in;
  const float* x  = (const float*)d_in[0];
  const float* ea = (const float*)d_in[1];
  const int*   e  = (const int*)d_in[2];
  const float* Wc = (const float*)d_in[3];
  const float* bc = (const float*)d_in[4];
  const float* Wi = (const float*)d_in[5];
  const float* bi = (const float*)d_in[6];
  const float* Wo = (const float*)d_in[7];
  const float* bo = (const float*)d_in[8];

  ushort* wsb = (ushort*)d_ws;
  ushort* Wcb = wsb + WS_WC;
  ushort* Wib = wsb + WS_WI;
  ushort* Wob = wsb + WS_WO;
  ushort* xb  = (ushort*)((char*)d_ws + WB_BYTES);
  float*  P12 = (float*)((char*)d_ws + WB_BYTES + XB_BYTES);

  cvt_w<<<dim3((512 * KC / 4 + 255) / 256), dim3(256), 0, stream>>>(Wc, Wcb, 512 * KC / 4);
  cvt_w<<<dim3((1536 * DD / 4 + 255) / 256), dim3(256), 0, stream>>>(Wi, Wib, 1536 * DD / 4);
  cvt_w<<<dim3((512 * DD / 4 + 255) / 256), dim3(256), 0, stream>>>(Wo, Wob, 512 * DD / 4);
  cvt_w<<<dim3((NNODE * DIN / 4 + 255) / 256), dim3(256), 0, stream>>>(x, xb, NNODE * DIN / 4);

  k0_p12<<<dim3(64, 8), dim3(256), 0, stream>>>(xb, Wcb, P12);

  float* out = (float*)d_out;
  hipMemsetAsync(out, 0, (size_t)out_size * sizeof(float), stream);

  // chunk sizing: 5 buffers (ex, Qn, Kn, Vt, AO), each C*32768 bytes
  size_t avail = ws_size > (size_t)CHUNK_OFF ? ws_size - (size_t)CHUNK_OFF : 0;
  long long Cll = (long long)(avail / 163840);
  int C = (int)(Cll > 8192 ? 8192 : Cll);
  C &= ~3;                      // multiple of 4 nodes (128-edge M-tiles)
  if (C < 4) C = 4;
  const size_t seg = (size_t)C * 32768;
  char* cbase = (char*)d_ws + CHUNK_OFF;
  ushort* exC = (ushort*)(cbase);
  ushort* Qn  = (ushort*)(cbase + seg);
  ushort* Kn  = (ushort*)(cbase + 2 * seg);
  ushort* Vt  = (ushort*)(cbase + 3 * seg);
  ushort* AO  = (ushort*)(cbase + 4 * seg);
  const int EC = C * 32;

  for (int n0 = 0; n0 < NNODE; n0 += C) {
    const int cc = (NNODE - n0 < C) ? (NNODE - n0) : C;
    k1_ex  <<<dim3(cc / 2), dim3(256), 0, stream>>>(ea, e, Wcb, bc, P12, exC, n0);
    k2a_qkv<<<dim3((cc / 4) * 12), dim3(256), 0, stream>>>(exC, Wib, bi, Qn, Kn, Vt, EC);
    k2b_attn<<<dim3(cc / 2), dim3(512), 0, stream>>>(Qn, Kn, Vt, AO, EC);
    k3_out <<<dim3((cc / 4) * 4), dim3(256), 0, stream>>>(AO, e, Wob, bo, out, n0);
  }
}

// Round 12
// 1879.782 us; speedup vs baseline: 1.3770x; 1.3770x over previous
//
#include <hip/hip_runtime.h>
#include <hip/hip_bf16.h>

#define NNODE 8192
#define DEG   32
#define DIN   256
#define EDIM  64
#define KC    576            // 2*DIN + EDIM
#define DD    512            // internal width D
#define MEDGE (NNODE*DEG)
#define EAWP  516            // 512 + 4 f32 pad (k1 LDS)

typedef __attribute__((ext_vector_type(8))) short short8;
typedef __attribute__((ext_vector_type(4))) short short4v;
typedef __attribute__((ext_vector_type(4))) float floatx4;
typedef __attribute__((ext_vector_type(4))) unsigned int uint4v;
typedef unsigned int u32;

__device__ __forceinline__ ushort f2bf(float f) {
  union { float f; unsigned int i; } v; v.f = f;
  return (ushort)((v.i + 0x7fffu + ((v.i >> 16) & 1u)) >> 16);
}
__device__ __forceinline__ u32 pk2(float a, float b) {
  return (u32)f2bf(a) | ((u32)f2bf(b) << 16);
}
__device__ __forceinline__ float gelu_f(float z) {
  return 0.5f * z * (1.0f + erff(z * 0.70710678118654752f));
}
__device__ __forceinline__ floatx4 zero4() { floatx4 v = {0.f, 0.f, 0.f, 0.f}; return v; }

__device__ __forceinline__ short8 ld_cvt8(const float* __restrict__ p) {
  floatx4 a = *(const floatx4*)(p);
  floatx4 b = *(const floatx4*)(p + 4);
  short8 r;
  r[0] = (short)f2bf(a[0]); r[1] = (short)f2bf(a[1]);
  r[2] = (short)f2bf(a[2]); r[3] = (short)f2bf(a[3]);
  r[4] = (short)f2bf(b[0]); r[5] = (short)f2bf(b[1]);
  r[6] = (short)f2bf(b[2]); r[7] = (short)f2bf(b[3]);
  return r;
}

#define MFMA16(a, b, c) __builtin_amdgcn_mfma_f32_16x16x32_bf16((a), (b), (c), 0, 0, 0)

// bijective XCD swizzle (m204): contiguous wgid chunks per XCD
__device__ __forceinline__ int xswz(int orig, int nwg) {
  const int q = nwg >> 3, r = nwg & 7;
  const int xcd = orig & 7, idx = orig >> 3;
  return (xcd < r ? xcd * (q + 1) : r * (q + 1) + (xcd - r) * q) + idx;
}

// D-layout -> A/B-frag-layout in-register transform (verified r2-r11).
__device__ __forceinline__ u32 bpsel(int a, u32 v0, u32 v1, bool hi) {
  u32 x0 = (u32)__builtin_amdgcn_ds_bpermute(a, (int)v0);
  u32 x1 = (u32)__builtin_amdgcn_ds_bpermute(a, (int)v1);
  return hi ? x1 : x0;
}
__device__ __forceinline__ short8 frag4(int a0, int a1, bool hi,
                                        u32 t00, u32 t01, u32 t10, u32 t11) {
  uint4v r;
  r[0] = bpsel(a0, t00, t10, hi);
  r[1] = bpsel(a0, t01, t11, hi);
  r[2] = bpsel(a1, t00, t10, hi);
  r[3] = bpsel(a1, t01, t11, hi);
  union { uint4v u; short8 s; } c; c.u = r; return c.s;
}

// async global -> LDS, 16 bytes per lane (wave-uniform LDS base + lane*16)
__device__ __forceinline__ void gl_lds16(const void* g, void* l) {
  __builtin_amdgcn_global_load_lds(
      (const __attribute__((address_space(1))) void*)g,
      (__attribute__((address_space(3))) void*)l,
      16, 0, 0);
}

// stage a [128 rows][64 k] bf16 tile (16 KB); gbase at (row0,k0); pitch in elems
__device__ __forceinline__ void stage_tile(const ushort* gbase, ushort* sdst,
                                           int tid, int pitch) {
  #pragma unroll
  for (int j = 0; j < 4; ++j) {
    const int off = (j * 256 + tid) * 16;   // byte offset in tile
    const int row = off >> 7;               // /128 (row = 128 B)
    const int kb  = off & 127;
    const char* g = (const char*)gbase + (size_t)row * (pitch * 2) + kb;
    char* l = (char*)sdst + j * 4096 + (tid >> 6) * 1024;   // wave-uniform
    gl_lds16(g, l);
  }
}

// ============================================================================
// K0 (tiled): P12 = Xb @ [Wc1^T | Wc2^T] (f32 out). grid (64, 8); 128x128 tile.
// ============================================================================
__global__ __launch_bounds__(256) void k0_p12(
    const ushort* __restrict__ xb, const ushort* __restrict__ Wcb,
    float* __restrict__ P12)
{
  __shared__ __align__(16) ushort sA[128 * 64];
  __shared__ __align__(16) ushort sB[128 * 64];

  const int bx   = blockIdx.x;
  const int nt8  = blockIdx.y;
  const int koff = (nt8 >= 4) ? 256 : 0;
  const int tid = threadIdx.x;
  const int w = tid >> 6, l = tid & 63, lr = l & 15, lg = l >> 4;
  const int wm = w >> 1, wn = w & 1;

  floatx4 acc[4][4];
  #pragma unroll
  for (int mt = 0; mt < 4; ++mt)
    #pragma unroll
    for (int nt = 0; nt < 4; ++nt) acc[mt][nt] = zero4();

  const ushort* gA = xb + (size_t)bx * 128 * DIN;
  const ushort* gB = Wcb + (size_t)((nt8 & 3) * 128) * KC + koff;

  for (int ks = 0; ks < 4; ++ks) {
    stage_tile(gA + ks * 64, sA, tid, DIN);
    stage_tile(gB + ks * 64, sB, tid, KC);
    __syncthreads();
    #pragma unroll
    for (int ksub = 0; ksub < 2; ++ksub) {
      short8 a[4], b[4];
      #pragma unroll
      for (int mt = 0; mt < 4; ++mt)
        a[mt] = *(const short8*)(&sA[(wm * 64 + mt * 16 + lr) * 64 + ksub * 32 + lg * 8]);
      #pragma unroll
      for (int nt = 0; nt < 4; ++nt)
        b[nt] = *(const short8*)(&sB[(wn * 64 + nt * 16 + lr) * 64 + ksub * 32 + lg * 8]);
      #pragma unroll
      for (int mt = 0; mt < 4; ++mt)
        #pragma unroll
        for (int nt = 0; nt < 4; ++nt)
          acc[mt][nt] = MFMA16(a[mt], b[nt], acc[mt][nt]);
    }
    __syncthreads();
  }
  const int c0 = nt8 * 128 + wn * 64;
  const int r0 = bx * 128 + wm * 64;
  #pragma unroll
  for (int mt = 0; mt < 4; ++mt)
    #pragma unroll
    for (int nt = 0; nt < 4; ++nt)
      #pragma unroll
      for (int i = 0; i < 4; ++i)
        P12[(size_t)(r0 + mt * 16 + lg * 4 + i) * 1024 + c0 + nt * 16 + lr] = acc[mt][nt][i];
}

// ============================================================================
// K1 (16-edge phases, 35 KB LDS -> 4 blocks/CU):
// ex = gelu(gelu(P1[src] + P2[dst] + ea@Wc3^T + bc)) -> exC [edge][512]
// ============================================================================
__global__ __launch_bounds__(256, 2) void k1_ex(
    const float* __restrict__ ea, const int* __restrict__ e,
    const ushort* __restrict__ Wcb, const float* __restrict__ bc,
    const float* __restrict__ P12,
    ushort* __restrict__ exC, int n0)
{
  __shared__ float sEAW[16 * EAWP];   // [16 edges][512] f32, pad 4  (33 KB)
  __shared__ float sP1B[512];         // P1[src] + bc

  const int m0  = (n0 + blockIdx.x * 2) * DEG;
  const int le0 = blockIdx.x * 64;
  const int tid = threadIdx.x;
  const int w = tid >> 6, l = tid & 63, lr = l & 15, lg = l >> 4;

  for (int nn = 0; nn < 2; ++nn) {
    for (int half = 0; half < 2; ++half) {
      const int eb = nn * 32 + half * 16;   // edge base within block
      if (half == 0 && tid < 128) {
        const int node = e[m0 + nn * DEG];
        floatx4 a = *(const floatx4*)(P12 + (size_t)node * 1024 + tid * 4);
        floatx4 b = *(const floatx4*)(bc + tid * 4);
        #pragma unroll
        for (int q = 0; q < 4; ++q) a[q] += b[q];
        *(floatx4*)(&sP1B[tid * 4]) = a;
      }
      // phase A: EAW = ea @ Wc3^T for 16 edges; wave w covers cols w*128..+128
      {
        floatx4 acc[8];
        #pragma unroll
        for (int nt = 0; nt < 8; ++nt) acc[nt] = zero4();
        #pragma unroll
        for (int s = 0; s < 2; ++s) {
          short8 af = ld_cvt8(ea + (size_t)(m0 + eb + lr) * EDIM + s * 32 + lg * 8);
          #pragma unroll
          for (int nt = 0; nt < 8; ++nt) {
            short8 bfr = *(const short8*)(Wcb + (size_t)(w * 128 + nt * 16 + lr) * KC + 512 + s * 32 + lg * 8);
            acc[nt] = MFMA16(af, bfr, acc[nt]);
          }
        }
        #pragma unroll
        for (int nt = 0; nt < 8; ++nt)
          #pragma unroll
          for (int i = 0; i < 4; ++i)
            sEAW[(lg * 4 + i) * EAWP + w * 128 + nt * 16 + lr] = acc[nt][i];
      }
      __syncthreads();

      // phase B: 16 threads per edge; contiguous 128 B per thread per j
      {
        const int eloc = tid >> 4;     // 0..15
        const int k16  = tid & 15;
        const int em   = m0 + eb + eloc;
        const int dn   = e[MEDGE + em];
        const float* p2r = P12 + (size_t)dn * 1024 + 512;
        const float* erow = &sEAW[eloc * EAWP];
        ushort* exrow = exC + (size_t)(le0 + eb + eloc) * DD;
        #pragma unroll
        for (int j = 0; j < 4; ++j) {
          const int col = j * 128 + k16 * 8;
          floatx4 q0 = *(const floatx4*)(p2r + col);
          floatx4 q1 = *(const floatx4*)(p2r + col + 4);
          floatx4 e0 = *(const floatx4*)(erow + col);
          floatx4 e1 = *(const floatx4*)(erow + col + 4);
          floatx4 b0 = *(const floatx4*)(&sP1B[col]);
          floatx4 b1 = *(const floatx4*)(&sP1B[col + 4]);
          short8 r;
          #pragma unroll
          for (int q = 0; q < 4; ++q) {
            r[q]     = (short)f2bf(gelu_f(gelu_f(e0[q] + b0[q] + q0[q])));
            r[4 + q] = (short)f2bf(gelu_f(gelu_f(e1[q] + b1[q] + q1[q])));
          }
          *(short8*)(exrow + col) = r;
        }
      }
      __syncthreads();
    }
  }
}

// ============================================================================
// K2a: QKV = exC @ Wi^T. 1-D grid (EC/128 * 12), XCD-swizzled, nt innermost.
// V epilogue: frag4 transpose -> fully coalesced 16 B stores into Vt[ch][edge].
// ============================================================================
__global__ __launch_bounds__(256) void k2a_qkv(
    const ushort* __restrict__ exC, const ushort* __restrict__ Wib,
    const float* __restrict__ bi,
    ushort* __restrict__ Qn, ushort* __restrict__ Kn, ushort* __restrict__ Vt,
    int EC)
{
  __shared__ __align__(16) ushort sA[128 * 64];
  __shared__ __align__(16) ushort sB[128 * 64];

  const int g    = xswz((int)blockIdx.x, (int)gridDim.x);
  const int bx   = g / 12;
  const int nt12 = g % 12;
  const int tid = threadIdx.x;
  const int w = tid >> 6, l = tid & 63, lr = l & 15, lg = l >> 4;
  const int wm = w >> 1, wn = w & 1;

  floatx4 acc[4][4];
  #pragma unroll
  for (int mt = 0; mt < 4; ++mt)
    #pragma unroll
    for (int nt = 0; nt < 4; ++nt) acc[mt][nt] = zero4();

  const ushort* gA = exC + (size_t)bx * 128 * DD;
  const ushort* gB = Wib + (size_t)nt12 * 128 * DD;

  for (int ks = 0; ks < 8; ++ks) {
    stage_tile(gA + ks * 64, sA, tid, DD);
    stage_tile(gB + ks * 64, sB, tid, DD);
    __syncthreads();
    #pragma unroll
    for (int ksub = 0; ksub < 2; ++ksub) {
      short8 a[4], b[4];
      #pragma unroll
      for (int mt = 0; mt < 4; ++mt)
        a[mt] = *(const short8*)(&sA[(wm * 64 + mt * 16 + lr) * 64 + ksub * 32 + lg * 8]);
      #pragma unroll
      for (int nt = 0; nt < 4; ++nt)
        b[nt] = *(const short8*)(&sB[(wn * 64 + nt * 16 + lr) * 64 + ksub * 32 + lg * 8]);
      #pragma unroll
      for (int mt = 0; mt < 4; ++mt)
        #pragma unroll
        for (int nt = 0; nt < 4; ++nt)
          acc[mt][nt] = MFMA16(a[mt], b[nt], acc[mt][nt]);
    }
    __syncthreads();
  }

  const int o0    = nt12 * 128 + wn * 64;
  const int seg   = o0 >> 9;
  const int h     = (o0 >> 6) & 7;
  const int ebase = bx * 128 + wm * 64;

  if (seg < 2) {
    ushort* Dst = (seg == 0 ? Qn : Kn) + (size_t)h * EC * 64;
    #pragma unroll
    for (int nt = 0; nt < 4; ++nt) {
      const int ch = nt * 16 + lr;
      const float bias = bi[o0 + ch];
      #pragma unroll
      for (int mt = 0; mt < 4; ++mt)
        #pragma unroll
        for (int i = 0; i < 4; ++i)
          Dst[(size_t)(ebase + mt * 16 + lg * 4 + i) * 64 + ch] = f2bf(acc[mt][nt][i] + bias);
    }
  } else {
    // V: transpose in-register (frag4) -> coalesced 16 B row stores
    ushort* Dv = Vt + (size_t)h * 64 * EC;
    const int pa0 = ((2 * (lg & 1)) * 16 + lr) * 4;
    const int pa1 = pa0 + 64;
    const bool hi = ((lg >> 1) & 1) != 0;
    #pragma unroll
    for (int nt = 0; nt < 4; ++nt) {
      const int ch = nt * 16 + lr;           // D-layout col (within head's 64)
      const float bias = bi[o0 + ch];
      u32 vpk[4][2];
      #pragma unroll
      for (int mt = 0; mt < 4; ++mt) {
        vpk[mt][0] = pk2(acc[mt][nt][0] + bias, acc[mt][nt][1] + bias);
        vpk[mt][1] = pk2(acc[mt][nt][2] + bias, acc[mt][nt][3] + bias);
      }
      #pragma unroll
      for (int mp = 0; mp < 2; ++mp) {
        short8 vf = frag4(pa0, pa1, hi, vpk[2*mp][0], vpk[2*mp][1],
                                        vpk[2*mp+1][0], vpk[2*mp+1][1]);
        // lane holds 8 consecutive edges of channel (pa-mapped lr): row = lr
        *(short8*)(&Dv[(size_t)(nt * 16 + lr) * EC + ebase + mp * 32 + lg * 8]) = vf;
      }
    }
  }
}

// ============================================================================
// K2b: attention (r11 verbatim). 512 thr / 8 waves, wave = head; 2 nodes/block.
// ============================================================================
__global__ __launch_bounds__(512, 3) void k2b_attn(
    const ushort* __restrict__ Qn, const ushort* __restrict__ Kn,
    const ushort* __restrict__ Vt,
    ushort* __restrict__ aoC, int EC)
{
  const int le0 = blockIdx.x * 64;
  const int tid = threadIdx.x;
  const int w = tid >> 6, l = tid & 63, lr = l & 15, lg = l >> 4;

  const ushort* Qh = Qn + (size_t)w * EC * 64;
  const ushort* Kh = Kn + (size_t)w * EC * 64;
  const ushort* Vh = Vt + (size_t)w * 64 * EC;

  const int pa0 = ((2 * (lg & 1)) * 16 + lr) * 4;
  const int pa1 = pa0 + 64;
  const bool hi = ((lg >> 1) & 1) != 0;

  #pragma unroll
  for (int n = 0; n < 2; ++n) {
    const int e0 = le0 + n * 32;

    floatx4 sacc[2][2];
    #pragma unroll
    for (int a = 0; a < 2; ++a)
      #pragma unroll
      for (int b = 0; b < 2; ++b) sacc[a][b] = zero4();
    #pragma unroll
    for (int ks2 = 0; ks2 < 2; ++ks2) {
      short8 kfr[2], qfr[2];
      #pragma unroll
      for (int mt = 0; mt < 2; ++mt)
        kfr[mt] = *(const short8*)(Kh + (size_t)(e0 + mt * 16 + lr) * 64 + ks2 * 32 + lg * 8);
      #pragma unroll
      for (int nt = 0; nt < 2; ++nt)
        qfr[nt] = *(const short8*)(Qh + (size_t)(e0 + nt * 16 + lr) * 64 + ks2 * 32 + lg * 8);
      #pragma unroll
      for (int mt = 0; mt < 2; ++mt)
        #pragma unroll
        for (int nt = 0; nt < 2; ++nt)
          sacc[mt][nt] = MFMA16(kfr[mt], qfr[nt], sacc[mt][nt]);
    }

    u32 ppk[2][4];
    #pragma unroll
    for (int nt = 0; nt < 2; ++nt) {
      float s[2][4];
      float mx = -1e30f;
      #pragma unroll
      for (int mt = 0; mt < 2; ++mt)
        #pragma unroll
        for (int i = 0; i < 4; ++i) {
          s[mt][i] = sacc[mt][nt][i] * 0.125f;
          mx = fmaxf(mx, s[mt][i]);
        }
      mx = fmaxf(mx, __shfl_xor(mx, 16));
      mx = fmaxf(mx, __shfl_xor(mx, 32));
      float sm = 0.f;
      #pragma unroll
      for (int mt = 0; mt < 2; ++mt)
        #pragma unroll
        for (int i = 0; i < 4; ++i) { s[mt][i] = expf(s[mt][i] - mx); sm += s[mt][i]; }
      sm += __shfl_xor(sm, 16);
      sm += __shfl_xor(sm, 32);
      const float inv = 1.0f / sm;
      #pragma unroll
      for (int mt = 0; mt < 2; ++mt) {
        ppk[mt][2 * nt + 0] = pk2(s[mt][0] * inv, s[mt][1] * inv);
        ppk[mt][2 * nt + 1] = pk2(s[mt][2] * inv, s[mt][3] * inv);
      }
    }

    short8 paf[2], vbf[4];
    #pragma unroll
    for (int qt = 0; qt < 2; ++qt)
      paf[qt] = frag4(pa0, pa1, hi, ppk[0][2 * qt + 0], ppk[0][2 * qt + 1],
                                    ppk[1][2 * qt + 0], ppk[1][2 * qt + 1]);
    #pragma unroll
    for (int nt = 0; nt < 4; ++nt)
      vbf[nt] = *(const short8*)(Vh + (size_t)(nt * 16 + lr) * EC + e0 + lg * 8);
    #pragma unroll
    for (int qt = 0; qt < 2; ++qt)
      #pragma unroll
      for (int nt = 0; nt < 4; ++nt) {
        floatx4 o = MFMA16(paf[qt], vbf[nt], zero4());
        #pragma unroll
        for (int i = 0; i < 4; ++i)
          aoC[(size_t)(e0 + qt * 16 + lg * 4 + i) * DD + w * 64 + nt * 16 + lr] = f2bf(o[i]);
      }
  }
}

// ============================================================================
// K3: h = gelu(AO @ Wo^T + bo) in-place, weighted-mean agg, atomic scatter.
// default launch bounds (no forced reg cap); XCD-swizzled 1-D grid.
// ============================================================================
__global__ __launch_bounds__(256) void k3_out(
    const ushort* __restrict__ aoC, const int* __restrict__ e,
    const ushort* __restrict__ Wob, const float* __restrict__ bo,
    float* __restrict__ out, int n0)
{
  __shared__ __align__(16) ushort sA[128 * 64];
  __shared__ __align__(16) ushort sB[128 * 64];

  const int g   = xswz((int)blockIdx.x, (int)gridDim.x);
  const int bx  = g >> 2;
  const int nt4 = g & 3;
  const int tid = threadIdx.x;
  const int w = tid >> 6, l = tid & 63, lr = l & 15, lg = l >> 4;
  const int wm = w >> 1, wn = w & 1;

  floatx4 acc[4][4];
  #pragma unroll
  for (int mt = 0; mt < 4; ++mt)
    #pragma unroll
    for (int nt = 0; nt < 4; ++nt) acc[mt][nt] = zero4();

  const ushort* gA = aoC + (size_t)bx * 128 * DD;
  const ushort* gB = Wob + (size_t)nt4 * 128 * DD;

  for (int ks = 0; ks < 8; ++ks) {
    stage_tile(gA + ks * 64, sA, tid, DD);
    stage_tile(gB + ks * 64, sB, tid, DD);
    __syncthreads();
    #pragma unroll
    for (int ksub = 0; ksub < 2; ++ksub) {
      short8 a[4], b[4];
      #pragma unroll
      for (int mt = 0; mt < 4; ++mt)
        a[mt] = *(const short8*)(&sA[(wm * 64 + mt * 16 + lr) * 64 + ksub * 32 + lg * 8]);
      #pragma unroll
      for (int nt = 0; nt < 4; ++nt)
        b[nt] = *(const short8*)(&sB[(wn * 64 + nt * 16 + lr) * 64 + ksub * 32 + lg * 8]);
      #pragma unroll
      for (int mt = 0; mt < 4; ++mt)
        #pragma unroll
        for (int nt = 0; nt < 4; ++nt)
          acc[mt][nt] = MFMA16(a[mt], b[nt], acc[mt][nt]);
    }
    __syncthreads();
  }

  const int head = nt4 * 2 + wn;
  #pragma unroll
  for (int nt = 0; nt < 4; ++nt) {
    const float bias = bo[nt4 * 128 + wn * 64 + nt * 16 + lr];
    #pragma unroll
    for (int mt = 0; mt < 4; ++mt)
      #pragma unroll
      for (int i = 0; i < 4; ++i)
        acc[mt][nt][i] = gelu_f(acc[mt][nt][i] + bias);
  }
  float lgA[4][4];
  #pragma unroll
  for (int mt = 0; mt < 4; ++mt)
    #pragma unroll
    for (int i = 0; i < 4; ++i) {
      float tA = acc[mt][2][i] + acc[mt][3][i];
      #pragma unroll
      for (int d2 = 1; d2 < 16; d2 <<= 1) tA += __shfl_xor(tA, d2);
      lgA[mt][i] = tA * (1.0f / 32.0f);
    }
  float eAv[4][4], iA[2];
  #pragma unroll
  for (int n = 0; n < 2; ++n) {
    float mx = -1e30f;
    #pragma unroll
    for (int m2 = 0; m2 < 2; ++m2)
      #pragma unroll
      for (int i = 0; i < 4; ++i) mx = fmaxf(mx, lgA[2 * n + m2][i]);
    mx = fmaxf(mx, __shfl_xor(mx, 16));
    mx = fmaxf(mx, __shfl_xor(mx, 32));
    float sA2 = 0.f;
    #pragma unroll
    for (int m2 = 0; m2 < 2; ++m2)
      #pragma unroll
      for (int i = 0; i < 4; ++i) {
        eAv[2 * n + m2][i] = expf(lgA[2 * n + m2][i] - mx);
        sA2 += eAv[2 * n + m2][i];
      }
    sA2 += __shfl_xor(sA2, 16);
    sA2 += __shfl_xor(sA2, 32);
    iA[n] = 1.0f / sA2;
  }
  const int em0 = (n0 + bx * 4) * DEG + wm * 64;
  #pragma unroll
  for (int mt = 0; mt < 4; ++mt)
    #pragma unroll
    for (int i = 0; i < 4; ++i) {
      const int r  = mt * 16 + lg * 4 + i;
      const int d1 = e[MEDGE + em0 + r];
      float* bp = out + (size_t)d1 * 256 + head * 32;
      const float aA = eAv[mt][i] * iA[mt >> 1];
      atomicAdd(bp + lr,      acc[mt][0][i] * aA);
      atomicAdd(bp + 16 + lr, acc[mt][1][i] * aA);
    }
}

// fp32 -> bf16 pre-convert
__global__ __launch_bounds__(256) void cvt_w(const float* __restrict__ src,
                                             ushort* __restrict__ dst, int n4)
{
  const int i = blockIdx.x * 256 + threadIdx.x;
  if (i < n4) {
    floatx4 v = *(const floatx4*)(src + (size_t)i * 4);
    short4v r;
    #pragma unroll
    for (int j = 0; j < 4; ++j) r[j] = (short)f2bf(v[j]);
    *(short4v*)(dst + (size_t)i * 4) = r;
  }
}

// ws layout: weights bf16 | xb bf16 (4 MB) | P12 f32 (33.5 MB) | chunk buffers
#define WS_WC 0
#define WS_WI (WS_WC + 512*KC)
#define WS_WO (WS_WI + 1536*DD)
#define WB_BYTES   2686976
#define XB_BYTES   4194304
#define P12_BYTES  33554432
#define CHUNK_OFF  (WB_BYTES + XB_BYTES + P12_BYTES)

extern "C" void kernel_launch(void* const* d_in, const int* in_sizes, int n_in,
                              void* d_out, int out_size, void* d_ws, size_t ws_size,
                              hipStream_t stream)
{
  (void)in_sizes; (void)n_in;
  const float* x  = (const float*)d_in[0];
  const float* ea = (const float*)d_in[1];
  const int*   e  = (const int*)d_in[2];
  const float* Wc = (const float*)d_in[3];
  const float* bc = (const float*)d_in[4];
  const float* Wi = (const float*)d_in[5];
  const float* bi = (const float*)d_in[6];
  const float* Wo = (const float*)d_in[7];
  const float* bo = (const float*)d_in[8];

  ushort* wsb = (ushort*)d_ws;
  ushort* Wcb = wsb + WS_WC;
  ushort* Wib = wsb + WS_WI;
  ushort* Wob = wsb + WS_WO;
  ushort* xb  = (ushort*)((char*)d_ws + WB_BYTES);
  float*  P12 = (float*)((char*)d_ws + WB_BYTES + XB_BYTES);

  cvt_w<<<dim3((512 * KC / 4 + 255) / 256), dim3(256), 0, stream>>>(Wc, Wcb, 512 * KC / 4);
  cvt_w<<<dim3((1536 * DD / 4 + 255) / 256), dim3(256), 0, stream>>>(Wi, Wib, 1536 * DD / 4);
  cvt_w<<<dim3((512 * DD / 4 + 255) / 256), dim3(256), 0, stream>>>(Wo, Wob, 512 * DD / 4);
  cvt_w<<<dim3((NNODE * DIN / 4 + 255) / 256), dim3(256), 0, stream>>>(x, xb, NNODE * DIN / 4);

  k0_p12<<<dim3(64, 8), dim3(256), 0, stream>>>(xb, Wcb, P12);

  float* out = (float*)d_out;
  hipMemsetAsync(out, 0, (size_t)out_size * sizeof(float), stream);

  // chunk sizing: 5 buffers (ex, Qn, Kn, Vt, AO), each C*32768 bytes
  size_t avail = ws_size > (size_t)CHUNK_OFF ? ws_size - (size_t)CHUNK_OFF : 0;
  long long Cll = (long long)(avail / 163840);
  int C = (int)(Cll > 8192 ? 8192 : Cll);
  C &= ~3;                      // multiple of 4 nodes (128-edge M-tiles)
  if (C < 4) C = 4;
  const size_t seg = (size_t)C * 32768;
  char* cbase = (char*)d_ws + CHUNK_OFF;
  ushort* exC = (ushort*)(cbase);
  ushort* Qn  = (ushort*)(cbase + seg);
  ushort* Kn  = (ushort*)(cbase + 2 * seg);
  ushort* Vt  = (ushort*)(cbase + 3 * seg);
  ushort* AO  = (ushort*)(cbase + 4 * seg);
  const int EC = C * 32;

  for (int n0 = 0; n0 < NNODE; n0 += C) {
    const int cc = (NNODE - n0 < C) ? (NNODE - n0) : C;
    k1_ex  <<<dim3(cc / 2), dim3(256), 0, stream>>>(ea, e, Wcb, bc, P12, exC, n0);
    k2a_qkv<<<dim3((cc / 4) * 12), dim3(256), 0, stream>>>(exC, Wib, bi, Qn, Kn, Vt, EC);
    k2b_attn<<<dim3(cc / 2), dim3(512), 0, stream>>>(Qn, Kn, Vt, AO, EC);
    k3_out <<<dim3((cc / 4) * 4), dim3(256), 0, stream>>>(AO, e, Wob, bo, out, n0);
  }
}

// Round 13
// 1759.322 us; speedup vs baseline: 1.4712x; 1.0685x over previous
//
#include <hip/hip_runtime.h>
#include <hip/hip_bf16.h>

#define NNODE 8192
#define DEG   32
#define DIN   256
#define EDIM  64
#define KC    576            // 2*DIN + EDIM
#define DD    512            // internal width D
#define MEDGE (NNODE*DEG)
#define EAWP  516            // 512 + 4 f32 pad (k1 LDS)

typedef __attribute__((ext_vector_type(8))) short short8;
typedef __attribute__((ext_vector_type(4))) short short4v;
typedef __attribute__((ext_vector_type(4))) float floatx4;
typedef __attribute__((ext_vector_type(4))) unsigned int uint4v;
typedef unsigned int u32;

__device__ __forceinline__ ushort f2bf(float f) {
  union { float f; unsigned int i; } v; v.f = f;
  return (ushort)((v.i + 0x7fffu + ((v.i >> 16) & 1u)) >> 16);
}
__device__ __forceinline__ u32 pk2(float a, float b) {
  return (u32)f2bf(a) | ((u32)f2bf(b) << 16);
}
__device__ __forceinline__ float gelu_f(float z) {
  return 0.5f * z * (1.0f + erff(z * 0.70710678118654752f));
}
__device__ __forceinline__ floatx4 zero4() { floatx4 v = {0.f, 0.f, 0.f, 0.f}; return v; }

__device__ __forceinline__ short8 ld_cvt8(const float* __restrict__ p) {
  floatx4 a = *(const floatx4*)(p);
  floatx4 b = *(const floatx4*)(p + 4);
  short8 r;
  r[0] = (short)f2bf(a[0]); r[1] = (short)f2bf(a[1]);
  r[2] = (short)f2bf(a[2]); r[3] = (short)f2bf(a[3]);
  r[4] = (short)f2bf(b[0]); r[5] = (short)f2bf(b[1]);
  r[6] = (short)f2bf(b[2]); r[7] = (short)f2bf(b[3]);
  return r;
}

#define MFMA16(a, b, c) __builtin_amdgcn_mfma_f32_16x16x32_bf16((a), (b), (c), 0, 0, 0)

// bijective XCD swizzle (m204): contiguous wgid chunks per XCD
__device__ __forceinline__ int xswz(int orig, int nwg) {
  const int q = nwg >> 3, r = nwg & 7;
  const int xcd = orig & 7, idx = orig >> 3;
  return (xcd < r ? xcd * (q + 1) : r * (q + 1) + (xcd - r) * q) + idx;
}

// D-layout -> A/B-frag-layout in-register transform (verified r2-r12).
__device__ __forceinline__ u32 bpsel(int a, u32 v0, u32 v1, bool hi) {
  u32 x0 = (u32)__builtin_amdgcn_ds_bpermute(a, (int)v0);
  u32 x1 = (u32)__builtin_amdgcn_ds_bpermute(a, (int)v1);
  return hi ? x1 : x0;
}
__device__ __forceinline__ short8 frag4(int a0, int a1, bool hi,
                                        u32 t00, u32 t01, u32 t10, u32 t11) {
  uint4v r;
  r[0] = bpsel(a0, t00, t10, hi);
  r[1] = bpsel(a0, t01, t11, hi);
  r[2] = bpsel(a1, t00, t10, hi);
  r[3] = bpsel(a1, t01, t11, hi);
  union { uint4v u; short8 s; } c; c.u = r; return c.s;
}

// async global -> LDS, 16 bytes per lane (wave-uniform LDS base + lane*16)
__device__ __forceinline__ void gl_lds16(const void* g, void* l) {
  __builtin_amdgcn_global_load_lds(
      (const __attribute__((address_space(1))) void*)g,
      (__attribute__((address_space(3))) void*)l,
      16, 0, 0);
}

// stage a [128 rows][64 k] bf16 tile (16 KB), T2-SWIZZLED (rule #21):
// LDS dest stays linear; the GLOBAL source column is pre-swizzled
// (kb ^= (row&7)<<4 — a permutation inside each 128 B row, coalescing intact).
// Readers must apply the same XOR (lds_frag below).
__device__ __forceinline__ void stage_tile(const ushort* gbase, ushort* sdst,
                                           int tid, int pitch) {
  #pragma unroll
  for (int j = 0; j < 4; ++j) {
    const int off = (j * 256 + tid) * 16;   // linear byte offset in tile
    const int row = off >> 7;               // /128 (row = 128 B)
    const int kb  = (off & 127) ^ ((row & 7) << 4);
    const char* g = (const char*)gbase + (size_t)row * (pitch * 2) + kb;
    char* l = (char*)sdst + j * 4096 + (tid >> 6) * 1024;   // wave-uniform
    gl_lds16(g, l);
  }
}

// swizzled fragment read: tile element (row, celem) lives at
// row*64 + (celem ^ ((row&7)<<3))   [elements; <<3 elems == <<4 bytes]
__device__ __forceinline__ short8 lds_frag(const ushort* s, int row, int celem) {
  return *(const short8*)(&s[row * 64 + (celem ^ ((row & 7) << 3))]);
}

// ============================================================================
// K0 (tiled): P12 = Xb @ [Wc1^T | Wc2^T] (f32 out). grid (64, 8); 128x128 tile.
// ============================================================================
__global__ __launch_bounds__(256) void k0_p12(
    const ushort* __restrict__ xb, const ushort* __restrict__ Wcb,
    float* __restrict__ P12)
{
  __shared__ __align__(16) ushort sA[128 * 64];
  __shared__ __align__(16) ushort sB[128 * 64];

  const int bx   = blockIdx.x;
  const int nt8  = blockIdx.y;
  const int koff = (nt8 >= 4) ? 256 : 0;
  const int tid = threadIdx.x;
  const int w = tid >> 6, l = tid & 63, lr = l & 15, lg = l >> 4;
  const int wm = w >> 1, wn = w & 1;

  floatx4 acc[4][4];
  #pragma unroll
  for (int mt = 0; mt < 4; ++mt)
    #pragma unroll
    for (int nt = 0; nt < 4; ++nt) acc[mt][nt] = zero4();

  const ushort* gA = xb + (size_t)bx * 128 * DIN;
  const ushort* gB = Wcb + (size_t)((nt8 & 3) * 128) * KC + koff;

  for (int ks = 0; ks < 4; ++ks) {
    stage_tile(gA + ks * 64, sA, tid, DIN);
    stage_tile(gB + ks * 64, sB, tid, KC);
    __syncthreads();
    #pragma unroll
    for (int ksub = 0; ksub < 2; ++ksub) {
      const int ce = ksub * 32 + lg * 8;
      short8 a[4], b[4];
      #pragma unroll
      for (int mt = 0; mt < 4; ++mt)
        a[mt] = lds_frag(sA, wm * 64 + mt * 16 + lr, ce);
      #pragma unroll
      for (int nt = 0; nt < 4; ++nt)
        b[nt] = lds_frag(sB, wn * 64 + nt * 16 + lr, ce);
      #pragma unroll
      for (int mt = 0; mt < 4; ++mt)
        #pragma unroll
        for (int nt = 0; nt < 4; ++nt)
          acc[mt][nt] = MFMA16(a[mt], b[nt], acc[mt][nt]);
    }
    __syncthreads();
  }
  const int c0 = nt8 * 128 + wn * 64;
  const int r0 = bx * 128 + wm * 64;
  #pragma unroll
  for (int mt = 0; mt < 4; ++mt)
    #pragma unroll
    for (int nt = 0; nt < 4; ++nt)
      #pragma unroll
      for (int i = 0; i < 4; ++i)
        P12[(size_t)(r0 + mt * 16 + lg * 4 + i) * 1024 + c0 + nt * 16 + lr] = acc[mt][nt][i];
}

// ============================================================================
// K1 (r12 verbatim): ex = gelu(gelu(P1[src] + P2[dst] + ea@Wc3^T + bc))
// ============================================================================
__global__ __launch_bounds__(256, 2) void k1_ex(
    const float* __restrict__ ea, const int* __restrict__ e,
    const ushort* __restrict__ Wcb, const float* __restrict__ bc,
    const float* __restrict__ P12,
    ushort* __restrict__ exC, int n0)
{
  __shared__ float sEAW[16 * EAWP];   // [16 edges][512] f32, pad 4  (33 KB)
  __shared__ float sP1B[512];         // P1[src] + bc

  const int m0  = (n0 + blockIdx.x * 2) * DEG;
  const int le0 = blockIdx.x * 64;
  const int tid = threadIdx.x;
  const int w = tid >> 6, l = tid & 63, lr = l & 15, lg = l >> 4;

  for (int nn = 0; nn < 2; ++nn) {
    for (int half = 0; half < 2; ++half) {
      const int eb = nn * 32 + half * 16;   // edge base within block
      if (half == 0 && tid < 128) {
        const int node = e[m0 + nn * DEG];
        floatx4 a = *(const floatx4*)(P12 + (size_t)node * 1024 + tid * 4);
        floatx4 b = *(const floatx4*)(bc + tid * 4);
        #pragma unroll
        for (int q = 0; q < 4; ++q) a[q] += b[q];
        *(floatx4*)(&sP1B[tid * 4]) = a;
      }
      {
        floatx4 acc[8];
        #pragma unroll
        for (int nt = 0; nt < 8; ++nt) acc[nt] = zero4();
        #pragma unroll
        for (int s = 0; s < 2; ++s) {
          short8 af = ld_cvt8(ea + (size_t)(m0 + eb + lr) * EDIM + s * 32 + lg * 8);
          #pragma unroll
          for (int nt = 0; nt < 8; ++nt) {
            short8 bfr = *(const short8*)(Wcb + (size_t)(w * 128 + nt * 16 + lr) * KC + 512 + s * 32 + lg * 8);
            acc[nt] = MFMA16(af, bfr, acc[nt]);
          }
        }
        #pragma unroll
        for (int nt = 0; nt < 8; ++nt)
          #pragma unroll
          for (int i = 0; i < 4; ++i)
            sEAW[(lg * 4 + i) * EAWP + w * 128 + nt * 16 + lr] = acc[nt][i];
      }
      __syncthreads();

      {
        const int eloc = tid >> 4;     // 0..15
        const int k16  = tid & 15;
        const int em   = m0 + eb + eloc;
        const int dn   = e[MEDGE + em];
        const float* p2r = P12 + (size_t)dn * 1024 + 512;
        const float* erow = &sEAW[eloc * EAWP];
        ushort* exrow = exC + (size_t)(le0 + eb + eloc) * DD;
        #pragma unroll
        for (int j = 0; j < 4; ++j) {
          const int col = j * 128 + k16 * 8;
          floatx4 q0 = *(const floatx4*)(p2r + col);
          floatx4 q1 = *(const floatx4*)(p2r + col + 4);
          floatx4 e0 = *(const floatx4*)(erow + col);
          floatx4 e1 = *(const floatx4*)(erow + col + 4);
          floatx4 b0 = *(const floatx4*)(&sP1B[col]);
          floatx4 b1 = *(const floatx4*)(&sP1B[col + 4]);
          short8 r;
          #pragma unroll
          for (int q = 0; q < 4; ++q) {
            r[q]     = (short)f2bf(gelu_f(gelu_f(e0[q] + b0[q] + q0[q])));
            r[4 + q] = (short)f2bf(gelu_f(gelu_f(e1[q] + b1[q] + q1[q])));
          }
          *(short8*)(exrow + col) = r;
        }
      }
      __syncthreads();
    }
  }
}

// ============================================================================
// K2a: QKV = exC @ Wi^T. 1-D grid (EC/128 * 12), XCD-swizzled, nt innermost.
// V epilogue: frag4 transpose -> coalesced 16 B stores into Vt[ch][edge].
// ============================================================================
__global__ __launch_bounds__(256) void k2a_qkv(
    const ushort* __restrict__ exC, const ushort* __restrict__ Wib,
    const float* __restrict__ bi,
    ushort* __restrict__ Qn, ushort* __restrict__ Kn, ushort* __restrict__ Vt,
    int EC)
{
  __shared__ __align__(16) ushort sA[128 * 64];
  __shared__ __align__(16) ushort sB[128 * 64];

  const int g    = xswz((int)blockIdx.x, (int)gridDim.x);
  const int bx   = g / 12;
  const int nt12 = g % 12;
  const int tid = threadIdx.x;
  const int w = tid >> 6, l = tid & 63, lr = l & 15, lg = l >> 4;
  const int wm = w >> 1, wn = w & 1;

  floatx4 acc[4][4];
  #pragma unroll
  for (int mt = 0; mt < 4; ++mt)
    #pragma unroll
    for (int nt = 0; nt < 4; ++nt) acc[mt][nt] = zero4();

  const ushort* gA = exC + (size_t)bx * 128 * DD;
  const ushort* gB = Wib + (size_t)nt12 * 128 * DD;

  for (int ks = 0; ks < 8; ++ks) {
    stage_tile(gA + ks * 64, sA, tid, DD);
    stage_tile(gB + ks * 64, sB, tid, DD);
    __syncthreads();
    #pragma unroll
    for (int ksub = 0; ksub < 2; ++ksub) {
      const int ce = ksub * 32 + lg * 8;
      short8 a[4], b[4];
      #pragma unroll
      for (int mt = 0; mt < 4; ++mt)
        a[mt] = lds_frag(sA, wm * 64 + mt * 16 + lr, ce);
      #pragma unroll
      for (int nt = 0; nt < 4; ++nt)
        b[nt] = lds_frag(sB, wn * 64 + nt * 16 + lr, ce);
      #pragma unroll
      for (int mt = 0; mt < 4; ++mt)
        #pragma unroll
        for (int nt = 0; nt < 4; ++nt)
          acc[mt][nt] = MFMA16(a[mt], b[nt], acc[mt][nt]);
    }
    __syncthreads();
  }

  const int o0    = nt12 * 128 + wn * 64;
  const int seg   = o0 >> 9;
  const int h     = (o0 >> 6) & 7;
  const int ebase = bx * 128 + wm * 64;

  if (seg < 2) {
    ushort* Dst = (seg == 0 ? Qn : Kn) + (size_t)h * EC * 64;
    #pragma unroll
    for (int nt = 0; nt < 4; ++nt) {
      const int ch = nt * 16 + lr;
      const float bias = bi[o0 + ch];
      #pragma unroll
      for (int mt = 0; mt < 4; ++mt)
        #pragma unroll
        for (int i = 0; i < 4; ++i)
          Dst[(size_t)(ebase + mt * 16 + lg * 4 + i) * 64 + ch] = f2bf(acc[mt][nt][i] + bias);
    }
  } else {
    // V: transpose in-register (frag4) -> coalesced 16 B row stores
    ushort* Dv = Vt + (size_t)h * 64 * EC;
    const int pa0 = ((2 * (lg & 1)) * 16 + lr) * 4;
    const int pa1 = pa0 + 64;
    const bool hi = ((lg >> 1) & 1) != 0;
    #pragma unroll
    for (int nt = 0; nt < 4; ++nt) {
      const int ch = nt * 16 + lr;
      const float bias = bi[o0 + ch];
      u32 vpk[4][2];
      #pragma unroll
      for (int mt = 0; mt < 4; ++mt) {
        vpk[mt][0] = pk2(acc[mt][nt][0] + bias, acc[mt][nt][1] + bias);
        vpk[mt][1] = pk2(acc[mt][nt][2] + bias, acc[mt][nt][3] + bias);
      }
      #pragma unroll
      for (int mp = 0; mp < 2; ++mp) {
        short8 vf = frag4(pa0, pa1, hi, vpk[2*mp][0], vpk[2*mp][1],
                                        vpk[2*mp+1][0], vpk[2*mp+1][1]);
        *(short8*)(&Dv[(size_t)(nt * 16 + lr) * EC + ebase + mp * 32 + lg * 8]) = vf;
      }
    }
  }
}

// ============================================================================
// K2b: attention (r12 verbatim). 512 thr / 8 waves, wave = head; 2 nodes/block.
// ============================================================================
__global__ __launch_bounds__(512, 3) void k2b_attn(
    const ushort* __restrict__ Qn, const ushort* __restrict__ Kn,
    const ushort* __restrict__ Vt,
    ushort* __restrict__ aoC, int EC)
{
  const int le0 = blockIdx.x * 64;
  const int tid = threadIdx.x;
  const int w = tid >> 6, l = tid & 63, lr = l & 15, lg = l >> 4;

  const ushort* Qh = Qn + (size_t)w * EC * 64;
  const ushort* Kh = Kn + (size_t)w * EC * 64;
  const ushort* Vh = Vt + (size_t)w * 64 * EC;

  const int pa0 = ((2 * (lg & 1)) * 16 + lr) * 4;
  const int pa1 = pa0 + 64;
  const bool hi = ((lg >> 1) & 1) != 0;

  #pragma unroll
  for (int n = 0; n < 2; ++n) {
    const int e0 = le0 + n * 32;

    floatx4 sacc[2][2];
    #pragma unroll
    for (int a = 0; a < 2; ++a)
      #pragma unroll
      for (int b = 0; b < 2; ++b) sacc[a][b] = zero4();
    #pragma unroll
    for (int ks2 = 0; ks2 < 2; ++ks2) {
      short8 kfr[2], qfr[2];
      #pragma unroll
      for (int mt = 0; mt < 2; ++mt)
        kfr[mt] = *(const short8*)(Kh + (size_t)(e0 + mt * 16 + lr) * 64 + ks2 * 32 + lg * 8);
      #pragma unroll
      for (int nt = 0; nt < 2; ++nt)
        qfr[nt] = *(const short8*)(Qh + (size_t)(e0 + nt * 16 + lr) * 64 + ks2 * 32 + lg * 8);
      #pragma unroll
      for (int mt = 0; mt < 2; ++mt)
        #pragma unroll
        for (int nt = 0; nt < 2; ++nt)
          sacc[mt][nt] = MFMA16(kfr[mt], qfr[nt], sacc[mt][nt]);
    }

    u32 ppk[2][4];
    #pragma unroll
    for (int nt = 0; nt < 2; ++nt) {
      float s[2][4];
      float mx = -1e30f;
      #pragma unroll
      for (int mt = 0; mt < 2; ++mt)
        #pragma unroll
        for (int i = 0; i < 4; ++i) {
          s[mt][i] = sacc[mt][nt][i] * 0.125f;
          mx = fmaxf(mx, s[mt][i]);
        }
      mx = fmaxf(mx, __shfl_xor(mx, 16));
      mx = fmaxf(mx, __shfl_xor(mx, 32));
      float sm = 0.f;
      #pragma unroll
      for (int mt = 0; mt < 2; ++mt)
        #pragma unroll
        for (int i = 0; i < 4; ++i) { s[mt][i] = expf(s[mt][i] - mx); sm += s[mt][i]; }
      sm += __shfl_xor(sm, 16);
      sm += __shfl_xor(sm, 32);
      const float inv = 1.0f / sm;
      #pragma unroll
      for (int mt = 0; mt < 2; ++mt) {
        ppk[mt][2 * nt + 0] = pk2(s[mt][0] * inv, s[mt][1] * inv);
        ppk[mt][2 * nt + 1] = pk2(s[mt][2] * inv, s[mt][3] * inv);
      }
    }

    short8 paf[2], vbf[4];
    #pragma unroll
    for (int qt = 0; qt < 2; ++qt)
      paf[qt] = frag4(pa0, pa1, hi, ppk[0][2 * qt + 0], ppk[0][2 * qt + 1],
                                    ppk[1][2 * qt + 0], ppk[1][2 * qt + 1]);
    #pragma unroll
    for (int nt = 0; nt < 4; ++nt)
      vbf[nt] = *(const short8*)(Vh + (size_t)(nt * 16 + lr) * EC + e0 + lg * 8);
    #pragma unroll
    for (int qt = 0; qt < 2; ++qt)
      #pragma unroll
      for (int nt = 0; nt < 4; ++nt) {
        floatx4 o = MFMA16(paf[qt], vbf[nt], zero4());
        #pragma unroll
        for (int i = 0; i < 4; ++i)
          aoC[(size_t)(e0 + qt * 16 + lg * 4 + i) * DD + w * 64 + nt * 16 + lr] = f2bf(o[i]);
      }
  }
}

// ============================================================================
// K3: h = gelu(AO @ Wo^T + bo) in-place, weighted-mean agg, atomic scatter.
// ============================================================================
__global__ __launch_bounds__(256) void k3_out(
    const ushort* __restrict__ aoC, const int* __restrict__ e,
    const ushort* __restrict__ Wob, const float* __restrict__ bo,
    float* __restrict__ out, int n0)
{
  __shared__ __align__(16) ushort sA[128 * 64];
  __shared__ __align__(16) ushort sB[128 * 64];

  const int g   = xswz((int)blockIdx.x, (int)gridDim.x);
  const int bx  = g >> 2;
  const int nt4 = g & 3;
  const int tid = threadIdx.x;
  const int w = tid >> 6, l = tid & 63, lr = l & 15, lg = l >> 4;
  const int wm = w >> 1, wn = w & 1;

  floatx4 acc[4][4];
  #pragma unroll
  for (int mt = 0; mt < 4; ++mt)
    #pragma unroll
    for (int nt = 0; nt < 4; ++nt) acc[mt][nt] = zero4();

  const ushort* gA = aoC + (size_t)bx * 128 * DD;
  const ushort* gB = Wob + (size_t)nt4 * 128 * DD;

  for (int ks = 0; ks < 8; ++ks) {
    stage_tile(gA + ks * 64, sA, tid, DD);
    stage_tile(gB + ks * 64, sB, tid, DD);
    __syncthreads();
    #pragma unroll
    for (int ksub = 0; ksub < 2; ++ksub) {
      const int ce = ksub * 32 + lg * 8;
      short8 a[4], b[4];
      #pragma unroll
      for (int mt = 0; mt < 4; ++mt)
        a[mt] = lds_frag(sA, wm * 64 + mt * 16 + lr, ce);
      #pragma unroll
      for (int nt = 0; nt < 4; ++nt)
        b[nt] = lds_frag(sB, wn * 64 + nt * 16 + lr, ce);
      #pragma unroll
      for (int mt = 0; mt < 4; ++mt)
        #pragma unroll
        for (int nt = 0; nt < 4; ++nt)
          acc[mt][nt] = MFMA16(a[mt], b[nt], acc[mt][nt]);
    }
    __syncthreads();
  }

  const int head = nt4 * 2 + wn;
  #pragma unroll
  for (int nt = 0; nt < 4; ++nt) {
    const float bias = bo[nt4 * 128 + wn * 64 + nt * 16 + lr];
    #pragma unroll
    for (int mt = 0; mt < 4; ++mt)
      #pragma unroll
      for (int i = 0; i < 4; ++i)
        acc[mt][nt][i] = gelu_f(acc[mt][nt][i] + bias);
  }
  float lgA[4][4];
  #pragma unroll
  for (int mt = 0; mt < 4; ++mt)
    #pragma unroll
    for (int i = 0; i < 4; ++i) {
      float tA = acc[mt][2][i] + acc[mt][3][i];
      #pragma unroll
      for (int d2 = 1; d2 < 16; d2 <<= 1) tA += __shfl_xor(tA, d2);
      lgA[mt][i] = tA * (1.0f / 32.0f);
    }
  float eAv[4][4], iA[2];
  #pragma unroll
  for (int n = 0; n < 2; ++n) {
    float mx = -1e30f;
    #pragma unroll
    for (int m2 = 0; m2 < 2; ++m2)
      #pragma unroll
      for (int i = 0; i < 4; ++i) mx = fmaxf(mx, lgA[2 * n + m2][i]);
    mx = fmaxf(mx, __shfl_xor(mx, 16));
    mx = fmaxf(mx, __shfl_xor(mx, 32));
    float sA2 = 0.f;
    #pragma unroll
    for (int m2 = 0; m2 < 2; ++m2)
      #pragma unroll
      for (int i = 0; i < 4; ++i) {
        eAv[2 * n + m2][i] = expf(lgA[2 * n + m2][i] - mx);
        sA2 += eAv[2 * n + m2][i];
      }
    sA2 += __shfl_xor(sA2, 16);
    sA2 += __shfl_xor(sA2, 32);
    iA[n] = 1.0f / sA2;
  }
  const int em0 = (n0 + bx * 4) * DEG + wm * 64;
  #pragma unroll
  for (int mt = 0; mt < 4; ++mt)
    #pragma unroll
    for (int i = 0; i < 4; ++i) {
      const int r  = mt * 16 + lg * 4 + i;
      const int d1 = e[MEDGE + em0 + r];
      float* bp = out + (size_t)d1 * 256 + head * 32;
      const float aA = eAv[mt][i] * iA[mt >> 1];
      atomicAdd(bp + lr,      acc[mt][0][i] * aA);
      atomicAdd(bp + 16 + lr, acc[mt][1][i] * aA);
    }
}

// fp32 -> bf16 pre-convert
__global__ __launch_bounds__(256) void cvt_w(const float* __restrict__ src,
                                             ushort* __restrict__ dst, int n4)
{
  const int i = blockIdx.x * 256 + threadIdx.x;
  if (i < n4) {
    floatx4 v = *(const floatx4*)(src + (size_t)i * 4);
    short4v r;
    #pragma unroll
    for (int j = 0; j < 4; ++j) r[j] = (short)f2bf(v[j]);
    *(short4v*)(dst + (size_t)i * 4) = r;
  }
}

// ws layout: weights bf16 | xb bf16 (4 MB) | P12 f32 (33.5 MB) | chunk buffers
#define WS_WC 0
#define WS_WI (WS_WC + 512*KC)
#define WS_WO (WS_WI + 1536*DD)
#define WB_BYTES   2686976
#define XB_BYTES   4194304
#define P12_BYTES  33554432
#define CHUNK_OFF  (WB_BYTES + XB_BYTES + P12_BYTES)

extern "C" void kernel_launch(void* const* d_in, const int* in_sizes, int n_in,
                              void* d_out, int out_size, void* d_ws, size_t ws_size,
                              hipStream_t stream)
{
  (void)in_sizes; (void)n_in;
  const float* x  = (const float*)d_in[0];
  const float* ea = (const float*)d_in[1];
  const int*   e  = (const int*)d_in[2];
  const float* Wc = (const float*)d_in[3];
  const float* bc = (const float*)d_in[4];
  const float* Wi = (const float*)d_in[5];
  const float* bi = (const float*)d_in[6];
  const float* Wo = (const float*)d_in[7];
  const float* bo = (const float*)d_in[8];

  ushort* wsb = (ushort*)d_ws;
  ushort* Wcb = wsb + WS_WC;
  ushort* Wib = wsb + WS_WI;
  ushort* Wob = wsb + WS_WO;
  ushort* xb  = (ushort*)((char*)d_ws + WB_BYTES);
  float*  P12 = (float*)((char*)d_ws + WB_BYTES + XB_BYTES);

  cvt_w<<<dim3((512 * KC / 4 + 255) / 256), dim3(256), 0, stream>>>(Wc, Wcb, 512 * KC / 4);
  cvt_w<<<dim3((1536 * DD / 4 + 255) / 256), dim3(256), 0, stream>>>(Wi, Wib, 1536 * DD / 4);
  cvt_w<<<dim3((512 * DD / 4 + 255) / 256), dim3(256), 0, stream>>>(Wo, Wob, 512 * DD / 4);
  cvt_w<<<dim3((NNODE * DIN / 4 + 255) / 256), dim3(256), 0, stream>>>(x, xb, NNODE * DIN / 4);

  k0_p12<<<dim3(64, 8), dim3(256), 0, stream>>>(xb, Wcb, P12);

  float* out = (float*)d_out;
  hipMemsetAsync(out, 0, (size_t)out_size * sizeof(float), stream);

  // chunk sizing: 5 buffers (ex, Qn, Kn, Vt, AO), each C*32768 bytes
  size_t avail = ws_size > (size_t)CHUNK_OFF ? ws_size - (size_t)CHUNK_OFF : 0;
  long long Cll = (long long)(avail / 163840);
  int C = (int)(Cll > 8192 ? 8192 : Cll);
  C &= ~3;                      // multiple of 4 nodes (128-edge M-tiles)
  if (C < 4) C = 4;
  const size_t seg = (size_t)C * 32768;
  char* cbase = (char*)d_ws + CHUNK_OFF;
  ushort* exC = (ushort*)(cbase);
  ushort* Qn  = (ushort*)(cbase + seg);
  ushort* Kn  = (ushort*)(cbase + 2 * seg);
  ushort* Vt  = (ushort*)(cbase + 3 * seg);
  ushort* AO  = (ushort*)(cbase + 4 * seg);
  const int EC = C * 32;

  for (int n0 = 0; n0 < NNODE; n0 += C) {
    const int cc = (NNODE - n0 < C) ? (NNODE - n0) : C;
    k1_ex  <<<dim3(cc / 2), dim3(256), 0, stream>>>(ea, e, Wcb, bc, P12, exC, n0);
    k2a_qkv<<<dim3((cc / 4) * 12), dim3(256), 0, stream>>>(exC, Wib, bi, Qn, Kn, Vt, EC);
    k2b_attn<<<dim3(cc / 2), dim3(512), 0, stream>>>(Qn, Kn, Vt, AO, EC);
    k3_out <<<dim3((cc / 4) * 4), dim3(256), 0, stream>>>(AO, e, Wob, bo, out, n0);
  }
}

// Round 14
// 1561.220 us; speedup vs baseline: 1.6579x; 1.1269x over previous
//
#include <hip/hip_runtime.h>
#include <hip/hip_bf16.h>

#define NNODE 8192
#define DEG   32
#define DIN   256
#define EDIM  64
#define KC    576            // 2*DIN + EDIM
#define DD    512            // internal width D
#define MEDGE (NNODE*DEG)
#define EAWP  516            // 512 + 4 f32 pad (k1 LDS)

typedef __attribute__((ext_vector_type(8))) short short8;
typedef __attribute__((ext_vector_type(4))) short short4v;
typedef __attribute__((ext_vector_type(4))) float floatx4;
typedef __attribute__((ext_vector_type(4))) unsigned int uint4v;
typedef unsigned int u32;

__device__ __forceinline__ ushort f2bf(float f) {
  union { float f; unsigned int i; } v; v.f = f;
  return (ushort)((v.i + 0x7fffu + ((v.i >> 16) & 1u)) >> 16);
}
__device__ __forceinline__ u32 pk2(float a, float b) {
  return (u32)f2bf(a) | ((u32)f2bf(b) << 16);
}
__device__ __forceinline__ float gelu_f(float z) {
  return 0.5f * z * (1.0f + erff(z * 0.70710678118654752f));
}
__device__ __forceinline__ floatx4 zero4() { floatx4 v = {0.f, 0.f, 0.f, 0.f}; return v; }

__device__ __forceinline__ short8 ld_cvt8(const float* __restrict__ p) {
  floatx4 a = *(const floatx4*)(p);
  floatx4 b = *(const floatx4*)(p + 4);
  short8 r;
  r[0] = (short)f2bf(a[0]); r[1] = (short)f2bf(a[1]);
  r[2] = (short)f2bf(a[2]); r[3] = (short)f2bf(a[3]);
  r[4] = (short)f2bf(b[0]); r[5] = (short)f2bf(b[1]);
  r[6] = (short)f2bf(b[2]); r[7] = (short)f2bf(b[3]);
  return r;
}

#define MFMA16(a, b, c) __builtin_amdgcn_mfma_f32_16x16x32_bf16((a), (b), (c), 0, 0, 0)

// bijective XCD swizzle (m204): contiguous wgid chunks per XCD
__device__ __forceinline__ int xswz(int orig, int nwg) {
  const int q = nwg >> 3, r = nwg & 7;
  const int xcd = orig & 7, idx = orig >> 3;
  return (xcd < r ? xcd * (q + 1) : r * (q + 1) + (xcd - r) * q) + idx;
}

// D-layout -> A/B-frag-layout in-register transform (verified r2-r13).
__device__ __forceinline__ u32 bpsel(int a, u32 v0, u32 v1, bool hi) {
  u32 x0 = (u32)__builtin_amdgcn_ds_bpermute(a, (int)v0);
  u32 x1 = (u32)__builtin_amdgcn_ds_bpermute(a, (int)v1);
  return hi ? x1 : x0;
}
__device__ __forceinline__ short8 frag4(int a0, int a1, bool hi,
                                        u32 t00, u32 t01, u32 t10, u32 t11) {
  uint4v r;
  r[0] = bpsel(a0, t00, t10, hi);
  r[1] = bpsel(a0, t01, t11, hi);
  r[2] = bpsel(a1, t00, t10, hi);
  r[3] = bpsel(a1, t01, t11, hi);
  union { uint4v u; short8 s; } c; c.u = r; return c.s;
}

// async global -> LDS, 16 bytes per lane (wave-uniform LDS base + lane*16)
__device__ __forceinline__ void gl_lds16(const void* g, void* l) {
  __builtin_amdgcn_global_load_lds(
      (const __attribute__((address_space(1))) void*)g,
      (__attribute__((address_space(3))) void*)l,
      16, 0, 0);
}

// stage a [128 rows][64 k] bf16 tile (16 KB), T2-SWIZZLED (rule #21):
// LDS linear; GLOBAL source column pre-swizzled (kb ^= (row&7)<<4).
__device__ __forceinline__ void stage_tile(const ushort* gbase, ushort* sdst,
                                           int tid, int pitch) {
  #pragma unroll
  for (int j = 0; j < 4; ++j) {
    const int off = (j * 256 + tid) * 16;   // linear byte offset in tile
    const int row = off >> 7;               // /128 (row = 128 B)
    const int kb  = (off & 127) ^ ((row & 7) << 4);
    const char* g = (const char*)gbase + (size_t)row * (pitch * 2) + kb;
    char* l = (char*)sdst + j * 4096 + (tid >> 6) * 1024;   // wave-uniform
    gl_lds16(g, l);
  }
}

// swizzled fragment read for 64-elem-row staged tiles
__device__ __forceinline__ short8 lds_frag(const ushort* s, int row, int celem) {
  return *(const short8*)(&s[row * 64 + (celem ^ ((row & 7) << 3))]);
}

// ============================================================================
// K0 (tiled): P12 = Xb @ [Wc1^T | Wc2^T] (f32 out). grid (64, 8); 128x128 tile.
// ============================================================================
__global__ __launch_bounds__(256) void k0_p12(
    const ushort* __restrict__ xb, const ushort* __restrict__ Wcb,
    float* __restrict__ P12)
{
  __shared__ __align__(16) ushort sA[128 * 64];
  __shared__ __align__(16) ushort sB[128 * 64];

  const int bx   = blockIdx.x;
  const int nt8  = blockIdx.y;
  const int koff = (nt8 >= 4) ? 256 : 0;
  const int tid = threadIdx.x;
  const int w = tid >> 6, l = tid & 63, lr = l & 15, lg = l >> 4;
  const int wm = w >> 1, wn = w & 1;

  floatx4 acc[4][4];
  #pragma unroll
  for (int mt = 0; mt < 4; ++mt)
    #pragma unroll
    for (int nt = 0; nt < 4; ++nt) acc[mt][nt] = zero4();

  const ushort* gA = xb + (size_t)bx * 128 * DIN;
  const ushort* gB = Wcb + (size_t)((nt8 & 3) * 128) * KC + koff;

  for (int ks = 0; ks < 4; ++ks) {
    stage_tile(gA + ks * 64, sA, tid, DIN);
    stage_tile(gB + ks * 64, sB, tid, KC);
    __syncthreads();
    #pragma unroll
    for (int ksub = 0; ksub < 2; ++ksub) {
      const int ce = ksub * 32 + lg * 8;
      short8 a[4], b[4];
      #pragma unroll
      for (int mt = 0; mt < 4; ++mt)
        a[mt] = lds_frag(sA, wm * 64 + mt * 16 + lr, ce);
      #pragma unroll
      for (int nt = 0; nt < 4; ++nt)
        b[nt] = lds_frag(sB, wn * 64 + nt * 16 + lr, ce);
      #pragma unroll
      for (int mt = 0; mt < 4; ++mt)
        #pragma unroll
        for (int nt = 0; nt < 4; ++nt)
          acc[mt][nt] = MFMA16(a[mt], b[nt], acc[mt][nt]);
    }
    __syncthreads();
  }
  const int c0 = nt8 * 128 + wn * 64;
  const int r0 = bx * 128 + wm * 64;
  #pragma unroll
  for (int mt = 0; mt < 4; ++mt)
    #pragma unroll
    for (int nt = 0; nt < 4; ++nt)
      #pragma unroll
      for (int i = 0; i < 4; ++i)
        P12[(size_t)(r0 + mt * 16 + lg * 4 + i) * 1024 + c0 + nt * 16 + lr] = acc[mt][nt][i];
}

// ============================================================================
// K1 (r13 verbatim): ex = gelu(gelu(P1[src] + P2[dst] + ea@Wc3^T + bc))
// ============================================================================
__global__ __launch_bounds__(256, 2) void k1_ex(
    const float* __restrict__ ea, const int* __restrict__ e,
    const ushort* __restrict__ Wcb, const float* __restrict__ bc,
    const float* __restrict__ P12,
    ushort* __restrict__ exC, int n0)
{
  __shared__ float sEAW[16 * EAWP];   // [16 edges][512] f32, pad 4  (33 KB)
  __shared__ float sP1B[512];         // P1[src] + bc

  const int m0  = (n0 + blockIdx.x * 2) * DEG;
  const int le0 = blockIdx.x * 64;
  const int tid = threadIdx.x;
  const int w = tid >> 6, l = tid & 63, lr = l & 15, lg = l >> 4;

  for (int nn = 0; nn < 2; ++nn) {
    for (int half = 0; half < 2; ++half) {
      const int eb = nn * 32 + half * 16;   // edge base within block
      if (half == 0 && tid < 128) {
        const int node = e[m0 + nn * DEG];
        floatx4 a = *(const floatx4*)(P12 + (size_t)node * 1024 + tid * 4);
        floatx4 b = *(const floatx4*)(bc + tid * 4);
        #pragma unroll
        for (int q = 0; q < 4; ++q) a[q] += b[q];
        *(floatx4*)(&sP1B[tid * 4]) = a;
      }
      {
        floatx4 acc[8];
        #pragma unroll
        for (int nt = 0; nt < 8; ++nt) acc[nt] = zero4();
        #pragma unroll
        for (int s = 0; s < 2; ++s) {
          short8 af = ld_cvt8(ea + (size_t)(m0 + eb + lr) * EDIM + s * 32 + lg * 8);
          #pragma unroll
          for (int nt = 0; nt < 8; ++nt) {
            short8 bfr = *(const short8*)(Wcb + (size_t)(w * 128 + nt * 16 + lr) * KC + 512 + s * 32 + lg * 8);
            acc[nt] = MFMA16(af, bfr, acc[nt]);
          }
        }
        #pragma unroll
        for (int nt = 0; nt < 8; ++nt)
          #pragma unroll
          for (int i = 0; i < 4; ++i)
            sEAW[(lg * 4 + i) * EAWP + w * 128 + nt * 16 + lr] = acc[nt][i];
      }
      __syncthreads();

      {
        const int eloc = tid >> 4;     // 0..15
        const int k16  = tid & 15;
        const int em   = m0 + eb + eloc;
        const int dn   = e[MEDGE + em];
        const float* p2r = P12 + (size_t)dn * 1024 + 512;
        const float* erow = &sEAW[eloc * EAWP];
        ushort* exrow = exC + (size_t)(le0 + eb + eloc) * DD;
        #pragma unroll
        for (int j = 0; j < 4; ++j) {
          const int col = j * 128 + k16 * 8;
          floatx4 q0 = *(const floatx4*)(p2r + col);
          floatx4 q1 = *(const floatx4*)(p2r + col + 4);
          floatx4 e0 = *(const floatx4*)(erow + col);
          floatx4 e1 = *(const floatx4*)(erow + col + 4);
          floatx4 b0 = *(const floatx4*)(&sP1B[col]);
          floatx4 b1 = *(const floatx4*)(&sP1B[col + 4]);
          short8 r;
          #pragma unroll
          for (int q = 0; q < 4; ++q) {
            r[q]     = (short)f2bf(gelu_f(gelu_f(e0[q] + b0[q] + q0[q])));
            r[4 + q] = (short)f2bf(gelu_f(gelu_f(e1[q] + b1[q] + q1[q])));
          }
          *(short8*)(exrow + col) = r;
        }
      }
      __syncthreads();
    }
  }
}

// ============================================================================
// K2a (r13 verbatim): QKV = exC @ Wi^T. 1-D grid (EC/128 * 12), XCD-swizzled.
// ============================================================================
__global__ __launch_bounds__(256) void k2a_qkv(
    const ushort* __restrict__ exC, const ushort* __restrict__ Wib,
    const float* __restrict__ bi,
    ushort* __restrict__ Qn, ushort* __restrict__ Kn, ushort* __restrict__ Vt,
    int EC)
{
  __shared__ __align__(16) ushort sA[128 * 64];
  __shared__ __align__(16) ushort sB[128 * 64];

  const int g    = xswz((int)blockIdx.x, (int)gridDim.x);
  const int bx   = g / 12;
  const int nt12 = g % 12;
  const int tid = threadIdx.x;
  const int w = tid >> 6, l = tid & 63, lr = l & 15, lg = l >> 4;
  const int wm = w >> 1, wn = w & 1;

  floatx4 acc[4][4];
  #pragma unroll
  for (int mt = 0; mt < 4; ++mt)
    #pragma unroll
    for (int nt = 0; nt < 4; ++nt) acc[mt][nt] = zero4();

  const ushort* gA = exC + (size_t)bx * 128 * DD;
  const ushort* gB = Wib + (size_t)nt12 * 128 * DD;

  for (int ks = 0; ks < 8; ++ks) {
    stage_tile(gA + ks * 64, sA, tid, DD);
    stage_tile(gB + ks * 64, sB, tid, DD);
    __syncthreads();
    #pragma unroll
    for (int ksub = 0; ksub < 2; ++ksub) {
      const int ce = ksub * 32 + lg * 8;
      short8 a[4], b[4];
      #pragma unroll
      for (int mt = 0; mt < 4; ++mt)
        a[mt] = lds_frag(sA, wm * 64 + mt * 16 + lr, ce);
      #pragma unroll
      for (int nt = 0; nt < 4; ++nt)
        b[nt] = lds_frag(sB, wn * 64 + nt * 16 + lr, ce);
      #pragma unroll
      for (int mt = 0; mt < 4; ++mt)
        #pragma unroll
        for (int nt = 0; nt < 4; ++nt)
          acc[mt][nt] = MFMA16(a[mt], b[nt], acc[mt][nt]);
    }
    __syncthreads();
  }

  const int o0    = nt12 * 128 + wn * 64;
  const int seg   = o0 >> 9;
  const int h     = (o0 >> 6) & 7;
  const int ebase = bx * 128 + wm * 64;

  if (seg < 2) {
    ushort* Dst = (seg == 0 ? Qn : Kn) + (size_t)h * EC * 64;
    #pragma unroll
    for (int nt = 0; nt < 4; ++nt) {
      const int ch = nt * 16 + lr;
      const float bias = bi[o0 + ch];
      #pragma unroll
      for (int mt = 0; mt < 4; ++mt)
        #pragma unroll
        for (int i = 0; i < 4; ++i)
          Dst[(size_t)(ebase + mt * 16 + lg * 4 + i) * 64 + ch] = f2bf(acc[mt][nt][i] + bias);
    }
  } else {
    // V: transpose in-register (frag4) -> coalesced 16 B row stores
    ushort* Dv = Vt + (size_t)h * 64 * EC;
    const int pa0 = ((2 * (lg & 1)) * 16 + lr) * 4;
    const int pa1 = pa0 + 64;
    const bool hi = ((lg >> 1) & 1) != 0;
    #pragma unroll
    for (int nt = 0; nt < 4; ++nt) {
      const int ch = nt * 16 + lr;
      const float bias = bi[o0 + ch];
      u32 vpk[4][2];
      #pragma unroll
      for (int mt = 0; mt < 4; ++mt) {
        vpk[mt][0] = pk2(acc[mt][nt][0] + bias, acc[mt][nt][1] + bias);
        vpk[mt][1] = pk2(acc[mt][nt][2] + bias, acc[mt][nt][3] + bias);
      }
      #pragma unroll
      for (int mp = 0; mp < 2; ++mp) {
        short8 vf = frag4(pa0, pa1, hi, vpk[2*mp][0], vpk[2*mp][1],
                                        vpk[2*mp+1][0], vpk[2*mp+1][1]);
        *(short8*)(&Dv[(size_t)(nt * 16 + lr) * EC + ebase + mp * 32 + lg * 8]) = vf;
      }
    }
  }
}

// ============================================================================
// K23 (FUSED k2b+k3): per block = 2 nodes (64 edges), 8 waves (wave = head).
// Phase 1: attention -> LDS sAO[64][512] (XOR-swizzled rows).
// Phase 2: GEMM3 (A from LDS, B=Wo direct from L2) + gelu + weighted-mean
//          + atomic scatter.
// ============================================================================
__global__ __launch_bounds__(512) void k23_attn_out(
    const ushort* __restrict__ Qn, const ushort* __restrict__ Kn,
    const ushort* __restrict__ Vt, const int* __restrict__ e,
    const ushort* __restrict__ Wob, const float* __restrict__ bo,
    float* __restrict__ out, int EC, int n0)
{
  __shared__ __align__(16) ushort sAO[64 * 512];   // 64 KB, swizzled per row

  const int le0 = blockIdx.x * 64;
  const int m0  = (n0 + blockIdx.x * 2) * DEG;
  const int tid = threadIdx.x;
  const int w = tid >> 6, l = tid & 63, lr = l & 15, lg = l >> 4;

  const ushort* Qh = Qn + (size_t)w * EC * 64;
  const ushort* Kh = Kn + (size_t)w * EC * 64;
  const ushort* Vh = Vt + (size_t)w * 64 * EC;

  const int pa0 = ((2 * (lg & 1)) * 16 + lr) * 4;
  const int pa1 = pa0 + 64;
  const bool hi = ((lg >> 1) & 1) != 0;

  // ---------------- phase 1: attention for head w, both nodes --------------
  #pragma unroll
  for (int n = 0; n < 2; ++n) {
    const int e0 = le0 + n * 32;

    floatx4 sacc[2][2];
    #pragma unroll
    for (int a = 0; a < 2; ++a)
      #pragma unroll
      for (int b = 0; b < 2; ++b) sacc[a][b] = zero4();
    #pragma unroll
    for (int ks2 = 0; ks2 < 2; ++ks2) {
      short8 kfr[2], qfr[2];
      #pragma unroll
      for (int mt = 0; mt < 2; ++mt)
        kfr[mt] = *(const short8*)(Kh + (size_t)(e0 + mt * 16 + lr) * 64 + ks2 * 32 + lg * 8);
      #pragma unroll
      for (int nt = 0; nt < 2; ++nt)
        qfr[nt] = *(const short8*)(Qh + (size_t)(e0 + nt * 16 + lr) * 64 + ks2 * 32 + lg * 8);
      #pragma unroll
      for (int mt = 0; mt < 2; ++mt)
        #pragma unroll
        for (int nt = 0; nt < 2; ++nt)
          sacc[mt][nt] = MFMA16(kfr[mt], qfr[nt], sacc[mt][nt]);
    }

    u32 ppk[2][4];
    #pragma unroll
    for (int nt = 0; nt < 2; ++nt) {
      float s[2][4];
      float mx = -1e30f;
      #pragma unroll
      for (int mt = 0; mt < 2; ++mt)
        #pragma unroll
        for (int i = 0; i < 4; ++i) {
          s[mt][i] = sacc[mt][nt][i] * 0.125f;
          mx = fmaxf(mx, s[mt][i]);
        }
      mx = fmaxf(mx, __shfl_xor(mx, 16));
      mx = fmaxf(mx, __shfl_xor(mx, 32));
      float sm = 0.f;
      #pragma unroll
      for (int mt = 0; mt < 2; ++mt)
        #pragma unroll
        for (int i = 0; i < 4; ++i) { s[mt][i] = expf(s[mt][i] - mx); sm += s[mt][i]; }
      sm += __shfl_xor(sm, 16);
      sm += __shfl_xor(sm, 32);
      const float inv = 1.0f / sm;
      #pragma unroll
      for (int mt = 0; mt < 2; ++mt) {
        ppk[mt][2 * nt + 0] = pk2(s[mt][0] * inv, s[mt][1] * inv);
        ppk[mt][2 * nt + 1] = pk2(s[mt][2] * inv, s[mt][3] * inv);
      }
    }

    short8 paf[2], vbf[4];
    #pragma unroll
    for (int qt = 0; qt < 2; ++qt)
      paf[qt] = frag4(pa0, pa1, hi, ppk[0][2 * qt + 0], ppk[0][2 * qt + 1],
                                    ppk[1][2 * qt + 0], ppk[1][2 * qt + 1]);
    #pragma unroll
    for (int nt = 0; nt < 4; ++nt)
      vbf[nt] = *(const short8*)(Vh + (size_t)(nt * 16 + lr) * EC + e0 + lg * 8);
    #pragma unroll
    for (int qt = 0; qt < 2; ++qt)
      #pragma unroll
      for (int nt = 0; nt < 4; ++nt) {
        floatx4 o = MFMA16(paf[qt], vbf[nt], zero4());
        #pragma unroll
        for (int i = 0; i < 4; ++i) {
          const int row = n * 32 + qt * 16 + lg * 4 + i;
          const int col = w * 64 + nt * 16 + lr;
          sAO[row * 512 + (col ^ ((row & 7) << 3))] = f2bf(o[i]);
        }
      }
  }
  __syncthreads();   // sAO complete

  // ---------------- phase 2: GEMM3 for head w (cols w*64..w*64+63) ---------
  floatx4 acc[4][4];
  #pragma unroll
  for (int mt = 0; mt < 4; ++mt)
    #pragma unroll
    for (int nt = 0; nt < 4; ++nt) acc[mt][nt] = zero4();

  for (int ks = 0; ks < 16; ++ks) {
    const int ce = ks * 32 + lg * 8;
    short8 b[4], a[4];
    #pragma unroll
    for (int nt = 0; nt < 4; ++nt)
      b[nt] = *(const short8*)(Wob + (size_t)(w * 64 + nt * 16 + lr) * DD + ce);
    #pragma unroll
    for (int mt = 0; mt < 4; ++mt) {
      const int row = mt * 16 + lr;
      a[mt] = *(const short8*)(&sAO[row * 512 + (ce ^ ((row & 7) << 3))]);
    }
    #pragma unroll
    for (int mt = 0; mt < 4; ++mt)
      #pragma unroll
      for (int nt = 0; nt < 4; ++nt)
        acc[mt][nt] = MFMA16(a[mt], b[nt], acc[mt][nt]);
  }

  // epilogue (k3 verbatim; head = w, edges m0..m0+63)
  #pragma unroll
  for (int nt = 0; nt < 4; ++nt) {
    const float bias = bo[w * 64 + nt * 16 + lr];
    #pragma unroll
    for (int mt = 0; mt < 4; ++mt)
      #pragma unroll
      for (int i = 0; i < 4; ++i)
        acc[mt][nt][i] = gelu_f(acc[mt][nt][i] + bias);
  }
  float lgA[4][4];
  #pragma unroll
  for (int mt = 0; mt < 4; ++mt)
    #pragma unroll
    for (int i = 0; i < 4; ++i) {
      float tA = acc[mt][2][i] + acc[mt][3][i];
      #pragma unroll
      for (int d2 = 1; d2 < 16; d2 <<= 1) tA += __shfl_xor(tA, d2);
      lgA[mt][i] = tA * (1.0f / 32.0f);
    }
  float eAv[4][4], iA[2];
  #pragma unroll
  for (int n = 0; n < 2; ++n) {
    float mx = -1e30f;
    #pragma unroll
    for (int m2 = 0; m2 < 2; ++m2)
      #pragma unroll
      for (int i = 0; i < 4; ++i) mx = fmaxf(mx, lgA[2 * n + m2][i]);
    mx = fmaxf(mx, __shfl_xor(mx, 16));
    mx = fmaxf(mx, __shfl_xor(mx, 32));
    float sA2 = 0.f;
    #pragma unroll
    for (int m2 = 0; m2 < 2; ++m2)
      #pragma unroll
      for (int i = 0; i < 4; ++i) {
        eAv[2 * n + m2][i] = expf(lgA[2 * n + m2][i] - mx);
        sA2 += eAv[2 * n + m2][i];
      }
    sA2 += __shfl_xor(sA2, 16);
    sA2 += __shfl_xor(sA2, 32);
    iA[n] = 1.0f / sA2;
  }
  #pragma unroll
  for (int mt = 0; mt < 4; ++mt)
    #pragma unroll
    for (int i = 0; i < 4; ++i) {
      const int r  = mt * 16 + lg * 4 + i;
      const int d1 = e[MEDGE + m0 + r];
      float* bp = out + (size_t)d1 * 256 + w * 32;
      const float aA = eAv[mt][i] * iA[mt >> 1];
      atomicAdd(bp + lr,      acc[mt][0][i] * aA);
      atomicAdd(bp + 16 + lr, acc[mt][1][i] * aA);
    }
}

// fp32 -> bf16 pre-convert
__global__ __launch_bounds__(256) void cvt_w(const float* __restrict__ src,
                                             ushort* __restrict__ dst, int n4)
{
  const int i = blockIdx.x * 256 + threadIdx.x;
  if (i < n4) {
    floatx4 v = *(const floatx4*)(src + (size_t)i * 4);
    short4v r;
    #pragma unroll
    for (int j = 0; j < 4; ++j) r[j] = (short)f2bf(v[j]);
    *(short4v*)(dst + (size_t)i * 4) = r;
  }
}

// ws layout: weights bf16 | xb bf16 (4 MB) | P12 f32 (33.5 MB) | chunk buffers
#define WS_WC 0
#define WS_WI (WS_WC + 512*KC)
#define WS_WO (WS_WI + 1536*DD)
#define WB_BYTES   2686976
#define XB_BYTES   4194304
#define P12_BYTES  33554432
#define CHUNK_OFF  (WB_BYTES + XB_BYTES + P12_BYTES)

extern "C" void kernel_launch(void* const* d_in, const int* in_sizes, int n_in,
                              void* d_out, int out_size, void* d_ws, size_t ws_size,
                              hipStream_t stream)
{
  (void)in_sizes; (void)n_in;
  const float* x  = (const float*)d_in[0];
  const float* ea = (const float*)d_in[1];
  const int*   e  = (const int*)d_in[2];
  const float* Wc = (const float*)d_in[3];
  const float* bc = (const float*)d_in[4];
  const float* Wi = (const float*)d_in[5];
  const float* bi = (const float*)d_in[6];
  const float* Wo = (const float*)d_in[7];
  const float* bo = (const float*)d_in[8];

  ushort* wsb = (ushort*)d_ws;
  ushort* Wcb = wsb + WS_WC;
  ushort* Wib = wsb + WS_WI;
  ushort* Wob = wsb + WS_WO;
  ushort* xb  = (ushort*)((char*)d_ws + WB_BYTES);
  float*  P12 = (float*)((char*)d_ws + WB_BYTES + XB_BYTES);

  cvt_w<<<dim3((512 * KC / 4 + 255) / 256), dim3(256), 0, stream>>>(Wc, Wcb, 512 * KC / 4);
  cvt_w<<<dim3((1536 * DD / 4 + 255) / 256), dim3(256), 0, stream>>>(Wi, Wib, 1536 * DD / 4);
  cvt_w<<<dim3((512 * DD / 4 + 255) / 256), dim3(256), 0, stream>>>(Wo, Wob, 512 * DD / 4);
  cvt_w<<<dim3((NNODE * DIN / 4 + 255) / 256), dim3(256), 0, stream>>>(x, xb, NNODE * DIN / 4);

  k0_p12<<<dim3(64, 8), dim3(256), 0, stream>>>(xb, Wcb, P12);

  float* out = (float*)d_out;
  hipMemsetAsync(out, 0, (size_t)out_size * sizeof(float), stream);

  // chunk sizing: 4 buffers (ex, Qn, Kn, Vt), each C*32768 bytes
  size_t avail = ws_size > (size_t)CHUNK_OFF ? ws_size - (size_t)CHUNK_OFF : 0;
  long long Cll = (long long)(avail / 131072);
  int C = (int)(Cll > 8192 ? 8192 : Cll);
  C &= ~3;                      // multiple of 4 nodes (128-edge M-tiles)
  if (C < 4) C = 4;
  const size_t seg = (size_t)C * 32768;
  char* cbase = (char*)d_ws + CHUNK_OFF;
  ushort* exC = (ushort*)(cbase);
  ushort* Qn  = (ushort*)(cbase + seg);
  ushort* Kn  = (ushort*)(cbase + 2 * seg);
  ushort* Vt  = (ushort*)(cbase + 3 * seg);
  const int EC = C * 32;

  for (int n0 = 0; n0 < NNODE; n0 += C) {
    const int cc = (NNODE - n0 < C) ? (NNODE - n0) : C;
    k1_ex  <<<dim3(cc / 2), dim3(256), 0, stream>>>(ea, e, Wcb, bc, P12, exC, n0);
    k2a_qkv<<<dim3((cc / 4) * 12), dim3(256), 0, stream>>>(exC, Wib, bi, Qn, Kn, Vt, EC);
    k23_attn_out<<<dim3(cc / 2), dim3(512), 0, stream>>>(Qn, Kn, Vt, e, Wob, bo, out, EC, n0);
  }
}

// Round 15
// 1392.425 us; speedup vs baseline: 1.8589x; 1.1212x over previous
//
#include <hip/hip_runtime.h>
#include <hip/hip_bf16.h>

#define NNODE 8192
#define DEG   32
#define DIN   256
#define EDIM  64
#define KC    576            // 2*DIN + EDIM
#define DD    512            // internal width D
#define MEDGE (NNODE*DEG)
#define EAWP  516            // 512 + 4 f32 pad (k1 LDS)

typedef __attribute__((ext_vector_type(8))) short short8;
typedef __attribute__((ext_vector_type(4))) short short4v;
typedef __attribute__((ext_vector_type(4))) float floatx4;
typedef __attribute__((ext_vector_type(4))) unsigned int uint4v;
typedef unsigned int u32;

__device__ __forceinline__ ushort f2bf(float f) {
  union { float f; unsigned int i; } v; v.f = f;
  return (ushort)((v.i + 0x7fffu + ((v.i >> 16) & 1u)) >> 16);
}
__device__ __forceinline__ u32 pk2(float a, float b) {
  return (u32)f2bf(a) | ((u32)f2bf(b) << 16);
}
__device__ __forceinline__ float gelu_f(float z) {
  return 0.5f * z * (1.0f + erff(z * 0.70710678118654752f));
}
__device__ __forceinline__ floatx4 zero4() { floatx4 v = {0.f, 0.f, 0.f, 0.f}; return v; }

__device__ __forceinline__ short8 ld_cvt8(const float* __restrict__ p) {
  floatx4 a = *(const floatx4*)(p);
  floatx4 b = *(const floatx4*)(p + 4);
  short8 r;
  r[0] = (short)f2bf(a[0]); r[1] = (short)f2bf(a[1]);
  r[2] = (short)f2bf(a[2]); r[3] = (short)f2bf(a[3]);
  r[4] = (short)f2bf(b[0]); r[5] = (short)f2bf(b[1]);
  r[6] = (short)f2bf(b[2]); r[7] = (short)f2bf(b[3]);
  return r;
}

#define MFMA16(a, b, c) __builtin_amdgcn_mfma_f32_16x16x32_bf16((a), (b), (c), 0, 0, 0)

// bijective XCD swizzle (m204): contiguous wgid chunks per XCD
__device__ __forceinline__ int xswz(int orig, int nwg) {
  const int q = nwg >> 3, r = nwg & 7;
  const int xcd = orig & 7, idx = orig >> 3;
  return (xcd < r ? xcd * (q + 1) : r * (q + 1) + (xcd - r) * q) + idx;
}

// D-layout -> A/B-frag-layout in-register transform (verified r2-r14).
__device__ __forceinline__ u32 bpsel(int a, u32 v0, u32 v1, bool hi) {
  u32 x0 = (u32)__builtin_amdgcn_ds_bpermute(a, (int)v0);
  u32 x1 = (u32)__builtin_amdgcn_ds_bpermute(a, (int)v1);
  return hi ? x1 : x0;
}
__device__ __forceinline__ short8 frag4(int a0, int a1, bool hi,
                                        u32 t00, u32 t01, u32 t10, u32 t11) {
  uint4v r;
  r[0] = bpsel(a0, t00, t10, hi);
  r[1] = bpsel(a0, t01, t11, hi);
  r[2] = bpsel(a1, t00, t10, hi);
  r[3] = bpsel(a1, t01, t11, hi);
  union { uint4v u; short8 s; } c; c.u = r; return c.s;
}

// async global -> LDS, 16 bytes per lane (wave-uniform LDS base + lane*16)
__device__ __forceinline__ void gl_lds16(const void* g, void* l) {
  __builtin_amdgcn_global_load_lds(
      (const __attribute__((address_space(1))) void*)g,
      (__attribute__((address_space(3))) void*)l,
      16, 0, 0);
}

// stage a [128 rows][64 k] bf16 tile (16 KB), T2-SWIZZLED (rule #21):
// LDS linear; GLOBAL source column pre-swizzled (kb ^= (row&7)<<4).
__device__ __forceinline__ void stage_tile(const ushort* gbase, ushort* sdst,
                                           int tid, int pitch) {
  #pragma unroll
  for (int j = 0; j < 4; ++j) {
    const int off = (j * 256 + tid) * 16;   // linear byte offset in tile
    const int row = off >> 7;               // /128 (row = 128 B)
    const int kb  = (off & 127) ^ ((row & 7) << 4);
    const char* g = (const char*)gbase + (size_t)row * (pitch * 2) + kb;
    char* l = (char*)sdst + j * 4096 + (tid >> 6) * 1024;   // wave-uniform
    gl_lds16(g, l);
  }
}

// swizzled fragment read for 64-elem-row staged tiles
__device__ __forceinline__ short8 lds_frag(const ushort* s, int row, int celem) {
  return *(const short8*)(&s[row * 64 + (celem ^ ((row & 7) << 3))]);
}

// ============================================================================
// K0 (tiled): P12 = Xb @ [Wc1^T | Wc2^T] (f32 out). grid (64, 8); 128x128 tile.
// ============================================================================
__global__ __launch_bounds__(256) void k0_p12(
    const ushort* __restrict__ xb, const ushort* __restrict__ Wcb,
    float* __restrict__ P12)
{
  __shared__ __align__(16) ushort sA[128 * 64];
  __shared__ __align__(16) ushort sB[128 * 64];

  const int bx   = blockIdx.x;
  const int nt8  = blockIdx.y;
  const int koff = (nt8 >= 4) ? 256 : 0;
  const int tid = threadIdx.x;
  const int w = tid >> 6, l = tid & 63, lr = l & 15, lg = l >> 4;
  const int wm = w >> 1, wn = w & 1;

  floatx4 acc[4][4];
  #pragma unroll
  for (int mt = 0; mt < 4; ++mt)
    #pragma unroll
    for (int nt = 0; nt < 4; ++nt) acc[mt][nt] = zero4();

  const ushort* gA = xb + (size_t)bx * 128 * DIN;
  const ushort* gB = Wcb + (size_t)((nt8 & 3) * 128) * KC + koff;

  for (int ks = 0; ks < 4; ++ks) {
    stage_tile(gA + ks * 64, sA, tid, DIN);
    stage_tile(gB + ks * 64, sB, tid, KC);
    __syncthreads();
    #pragma unroll
    for (int ksub = 0; ksub < 2; ++ksub) {
      const int ce = ksub * 32 + lg * 8;
      short8 a[4], b[4];
      #pragma unroll
      for (int mt = 0; mt < 4; ++mt)
        a[mt] = lds_frag(sA, wm * 64 + mt * 16 + lr, ce);
      #pragma unroll
      for (int nt = 0; nt < 4; ++nt)
        b[nt] = lds_frag(sB, wn * 64 + nt * 16 + lr, ce);
      #pragma unroll
      for (int mt = 0; mt < 4; ++mt)
        #pragma unroll
        for (int nt = 0; nt < 4; ++nt)
          acc[mt][nt] = MFMA16(a[mt], b[nt], acc[mt][nt]);
    }
    __syncthreads();
  }
  const int c0 = nt8 * 128 + wn * 64;
  const int r0 = bx * 128 + wm * 64;
  #pragma unroll
  for (int mt = 0; mt < 4; ++mt)
    #pragma unroll
    for (int nt = 0; nt < 4; ++nt)
      #pragma unroll
      for (int i = 0; i < 4; ++i)
        P12[(size_t)(r0 + mt * 16 + lg * 4 + i) * 1024 + c0 + nt * 16 + lr] = acc[mt][nt][i];
}

// ============================================================================
// K1 (r14 verbatim): ex = gelu(gelu(P1[src] + P2[dst] + ea@Wc3^T + bc))
// ============================================================================
__global__ __launch_bounds__(256, 2) void k1_ex(
    const float* __restrict__ ea, const int* __restrict__ e,
    const ushort* __restrict__ Wcb, const float* __restrict__ bc,
    const float* __restrict__ P12,
    ushort* __restrict__ exC, int n0)
{
  __shared__ float sEAW[16 * EAWP];   // [16 edges][512] f32, pad 4  (33 KB)
  __shared__ float sP1B[512];         // P1[src] + bc

  const int m0  = (n0 + blockIdx.x * 2) * DEG;
  const int le0 = blockIdx.x * 64;
  const int tid = threadIdx.x;
  const int w = tid >> 6, l = tid & 63, lr = l & 15, lg = l >> 4;

  for (int nn = 0; nn < 2; ++nn) {
    for (int half = 0; half < 2; ++half) {
      const int eb = nn * 32 + half * 16;   // edge base within block
      if (half == 0 && tid < 128) {
        const int node = e[m0 + nn * DEG];
        floatx4 a = *(const floatx4*)(P12 + (size_t)node * 1024 + tid * 4);
        floatx4 b = *(const floatx4*)(bc + tid * 4);
        #pragma unroll
        for (int q = 0; q < 4; ++q) a[q] += b[q];
        *(floatx4*)(&sP1B[tid * 4]) = a;
      }
      {
        floatx4 acc[8];
        #pragma unroll
        for (int nt = 0; nt < 8; ++nt) acc[nt] = zero4();
        #pragma unroll
        for (int s = 0; s < 2; ++s) {
          short8 af = ld_cvt8(ea + (size_t)(m0 + eb + lr) * EDIM + s * 32 + lg * 8);
          #pragma unroll
          for (int nt = 0; nt < 8; ++nt) {
            short8 bfr = *(const short8*)(Wcb + (size_t)(w * 128 + nt * 16 + lr) * KC + 512 + s * 32 + lg * 8);
            acc[nt] = MFMA16(af, bfr, acc[nt]);
          }
        }
        #pragma unroll
        for (int nt = 0; nt < 8; ++nt)
          #pragma unroll
          for (int i = 0; i < 4; ++i)
            sEAW[(lg * 4 + i) * EAWP + w * 128 + nt * 16 + lr] = acc[nt][i];
      }
      __syncthreads();

      {
        const int eloc = tid >> 4;     // 0..15
        const int k16  = tid & 15;
        const int em   = m0 + eb + eloc;
        const int dn   = e[MEDGE + em];
        const float* p2r = P12 + (size_t)dn * 1024 + 512;
        const float* erow = &sEAW[eloc * EAWP];
        ushort* exrow = exC + (size_t)(le0 + eb + eloc) * DD;
        #pragma unroll
        for (int j = 0; j < 4; ++j) {
          const int col = j * 128 + k16 * 8;
          floatx4 q0 = *(const floatx4*)(p2r + col);
          floatx4 q1 = *(const floatx4*)(p2r + col + 4);
          floatx4 e0 = *(const floatx4*)(erow + col);
          floatx4 e1 = *(const floatx4*)(erow + col + 4);
          floatx4 b0 = *(const floatx4*)(&sP1B[col]);
          floatx4 b1 = *(const floatx4*)(&sP1B[col + 4]);
          short8 r;
          #pragma unroll
          for (int q = 0; q < 4; ++q) {
            r[q]     = (short)f2bf(gelu_f(gelu_f(e0[q] + b0[q] + q0[q])));
            r[4 + q] = (short)f2bf(gelu_f(gelu_f(e1[q] + b1[q] + q1[q])));
          }
          *(short8*)(exrow + col) = r;
        }
      }
      __syncthreads();
    }
  }
}

// ============================================================================
// K2a: QKV = exC @ Wi^T. 1-D grid (EC/128 * 12), XCD-swizzled.
// Q,K as before; V stored FRAG-NATIVE: Vf[h][(edge/32)][nt][lane] 16B units.
// ============================================================================
__global__ __launch_bounds__(256) void k2a_qkv(
    const ushort* __restrict__ exC, const ushort* __restrict__ Wib,
    const float* __restrict__ bi,
    ushort* __restrict__ Qn, ushort* __restrict__ Kn, ushort* __restrict__ Vt,
    int EC)
{
  __shared__ __align__(16) ushort sA[128 * 64];
  __shared__ __align__(16) ushort sB[128 * 64];

  const int g    = xswz((int)blockIdx.x, (int)gridDim.x);
  const int bx   = g / 12;
  const int nt12 = g % 12;
  const int tid = threadIdx.x;
  const int w = tid >> 6, l = tid & 63, lr = l & 15, lg = l >> 4;
  const int wm = w >> 1, wn = w & 1;

  floatx4 acc[4][4];
  #pragma unroll
  for (int mt = 0; mt < 4; ++mt)
    #pragma unroll
    for (int nt = 0; nt < 4; ++nt) acc[mt][nt] = zero4();

  const ushort* gA = exC + (size_t)bx * 128 * DD;
  const ushort* gB = Wib + (size_t)nt12 * 128 * DD;

  for (int ks = 0; ks < 8; ++ks) {
    stage_tile(gA + ks * 64, sA, tid, DD);
    stage_tile(gB + ks * 64, sB, tid, DD);
    __syncthreads();
    #pragma unroll
    for (int ksub = 0; ksub < 2; ++ksub) {
      const int ce = ksub * 32 + lg * 8;
      short8 a[4], b[4];
      #pragma unroll
      for (int mt = 0; mt < 4; ++mt)
        a[mt] = lds_frag(sA, wm * 64 + mt * 16 + lr, ce);
      #pragma unroll
      for (int nt = 0; nt < 4; ++nt)
        b[nt] = lds_frag(sB, wn * 64 + nt * 16 + lr, ce);
      #pragma unroll
      for (int mt = 0; mt < 4; ++mt)
        #pragma unroll
        for (int nt = 0; nt < 4; ++nt)
          acc[mt][nt] = MFMA16(a[mt], b[nt], acc[mt][nt]);
    }
    __syncthreads();
  }

  const int o0    = nt12 * 128 + wn * 64;
  const int seg   = o0 >> 9;
  const int h     = (o0 >> 6) & 7;
  const int ebase = bx * 128 + wm * 64;

  if (seg < 2) {
    ushort* Dst = (seg == 0 ? Qn : Kn) + (size_t)h * EC * 64;
    #pragma unroll
    for (int nt = 0; nt < 4; ++nt) {
      const int ch = nt * 16 + lr;
      const float bias = bi[o0 + ch];
      #pragma unroll
      for (int mt = 0; mt < 4; ++mt)
        #pragma unroll
        for (int i = 0; i < 4; ++i)
          Dst[(size_t)(ebase + mt * 16 + lg * 4 + i) * 64 + ch] = f2bf(acc[mt][nt][i] + bias);
    }
  } else {
    // V: frag4 transpose -> FRAG-NATIVE store. After frag4, lane(lg,lr) holds
    // 8 consecutive edges (ebase+mp*32+lg*8..) of channel nt*16+lr — exactly
    // k23's vbf lane content. Store at [h][g32][nt][l]*8, fully coalesced.
    ushort* Dv = Vt + (size_t)h * 64 * EC;
    const int pa0 = ((2 * (lg & 1)) * 16 + lr) * 4;
    const int pa1 = pa0 + 64;
    const bool hi = ((lg >> 1) & 1) != 0;
    #pragma unroll
    for (int nt = 0; nt < 4; ++nt) {
      const int ch = nt * 16 + lr;
      const float bias = bi[o0 + ch];
      u32 vpk[4][2];
      #pragma unroll
      for (int mt = 0; mt < 4; ++mt) {
        vpk[mt][0] = pk2(acc[mt][nt][0] + bias, acc[mt][nt][1] + bias);
        vpk[mt][1] = pk2(acc[mt][nt][2] + bias, acc[mt][nt][3] + bias);
      }
      #pragma unroll
      for (int mp = 0; mp < 2; ++mp) {
        short8 vf = frag4(pa0, pa1, hi, vpk[2*mp][0], vpk[2*mp][1],
                                        vpk[2*mp+1][0], vpk[2*mp+1][1]);
        const int g32 = (ebase + mp * 32) >> 5;
        *(short8*)(&Dv[(((size_t)g32 * 4 + nt) * 64 + l) * 8]) = vf;
      }
    }
  }
}

// pack Wo (bf16, row-major [512][512]) into frag-native order:
// Wof[((h*16+ks)*4+nt)*64 + l] (16B units) = Wo[h*64+nt*16+(l&15)][ks*32+(l>>4)*8 ..+8]
__global__ __launch_bounds__(256) void pack_wof(const ushort* __restrict__ Wob,
                                                ushort* __restrict__ Wof)
{
  const int idx = blockIdx.x * 256 + threadIdx.x;   // 0..32767
  const int l = idx & 63, t = idx >> 6;
  const int nt = t & 3, hk = t >> 2;
  const int ks = hk & 15, h = hk >> 4;
  const int lr = l & 15, lg = l >> 4;
  short8 v = *(const short8*)(Wob + (size_t)(h * 64 + nt * 16 + lr) * DD + ks * 32 + lg * 8);
  *(short8*)(Wof + (size_t)idx * 8) = v;
}

// ============================================================================
// K23 (fused attn + out): per block = 2 nodes (64 edges), 8 waves (wave=head).
// Phase 1: attention -> LDS sAO (XOR-swizzled). V loads frag-native (coalesced).
// Phase 2: GEMM3 with B from FRAG-NATIVE Wof (coalesced) + epilogue + scatter.
// ============================================================================
__global__ __launch_bounds__(512) void k23_attn_out(
    const ushort* __restrict__ Qn, const ushort* __restrict__ Kn,
    const ushort* __restrict__ Vt, const int* __restrict__ e,
    const ushort* __restrict__ Wof, const float* __restrict__ bo,
    float* __restrict__ out, int EC, int n0)
{
  __shared__ __align__(16) ushort sAO[64 * 512];   // 64 KB, swizzled per row

  const int le0 = blockIdx.x * 64;
  const int m0  = (n0 + blockIdx.x * 2) * DEG;
  const int tid = threadIdx.x;
  const int w = tid >> 6, l = tid & 63, lr = l & 15, lg = l >> 4;

  const ushort* Qh = Qn + (size_t)w * EC * 64;
  const ushort* Kh = Kn + (size_t)w * EC * 64;
  const ushort* Vh = Vt + (size_t)w * 64 * EC;

  const int pa0 = ((2 * (lg & 1)) * 16 + lr) * 4;
  const int pa1 = pa0 + 64;
  const bool hi = ((lg >> 1) & 1) != 0;

  // ---------------- phase 1: attention for head w, both nodes --------------
  #pragma unroll
  for (int n = 0; n < 2; ++n) {
    const int e0 = le0 + n * 32;

    floatx4 sacc[2][2];
    #pragma unroll
    for (int a = 0; a < 2; ++a)
      #pragma unroll
      for (int b = 0; b < 2; ++b) sacc[a][b] = zero4();
    #pragma unroll
    for (int ks2 = 0; ks2 < 2; ++ks2) {
      short8 kfr[2], qfr[2];
      #pragma unroll
      for (int mt = 0; mt < 2; ++mt)
        kfr[mt] = *(const short8*)(Kh + (size_t)(e0 + mt * 16 + lr) * 64 + ks2 * 32 + lg * 8);
      #pragma unroll
      for (int nt = 0; nt < 2; ++nt)
        qfr[nt] = *(const short8*)(Qh + (size_t)(e0 + nt * 16 + lr) * 64 + ks2 * 32 + lg * 8);
      #pragma unroll
      for (int mt = 0; mt < 2; ++mt)
        #pragma unroll
        for (int nt = 0; nt < 2; ++nt)
          sacc[mt][nt] = MFMA16(kfr[mt], qfr[nt], sacc[mt][nt]);
    }

    u32 ppk[2][4];
    #pragma unroll
    for (int nt = 0; nt < 2; ++nt) {
      float s[2][4];
      float mx = -1e30f;
      #pragma unroll
      for (int mt = 0; mt < 2; ++mt)
        #pragma unroll
        for (int i = 0; i < 4; ++i) {
          s[mt][i] = sacc[mt][nt][i] * 0.125f;
          mx = fmaxf(mx, s[mt][i]);
        }
      mx = fmaxf(mx, __shfl_xor(mx, 16));
      mx = fmaxf(mx, __shfl_xor(mx, 32));
      float sm = 0.f;
      #pragma unroll
      for (int mt = 0; mt < 2; ++mt)
        #pragma unroll
        for (int i = 0; i < 4; ++i) { s[mt][i] = expf(s[mt][i] - mx); sm += s[mt][i]; }
      sm += __shfl_xor(sm, 16);
      sm += __shfl_xor(sm, 32);
      const float inv = 1.0f / sm;
      #pragma unroll
      for (int mt = 0; mt < 2; ++mt) {
        ppk[mt][2 * nt + 0] = pk2(s[mt][0] * inv, s[mt][1] * inv);
        ppk[mt][2 * nt + 1] = pk2(s[mt][2] * inv, s[mt][3] * inv);
      }
    }

    short8 paf[2], vbf[4];
    #pragma unroll
    for (int qt = 0; qt < 2; ++qt)
      paf[qt] = frag4(pa0, pa1, hi, ppk[0][2 * qt + 0], ppk[0][2 * qt + 1],
                                    ppk[1][2 * qt + 0], ppk[1][2 * qt + 1]);
    {
      const int g32 = (e0) >> 5;
      #pragma unroll
      for (int nt = 0; nt < 4; ++nt)
        vbf[nt] = *(const short8*)(Vh + (((size_t)g32 * 4 + nt) * 64 + l) * 8);
    }
    #pragma unroll
    for (int qt = 0; qt < 2; ++qt)
      #pragma unroll
      for (int nt = 0; nt < 4; ++nt) {
        floatx4 o = MFMA16(paf[qt], vbf[nt], zero4());
        #pragma unroll
        for (int i = 0; i < 4; ++i) {
          const int row = n * 32 + qt * 16 + lg * 4 + i;
          const int col = w * 64 + nt * 16 + lr;
          sAO[row * 512 + (col ^ ((row & 7) << 3))] = f2bf(o[i]);
        }
      }
  }
  __syncthreads();   // sAO complete

  // ---------------- phase 2: GEMM3 for head w (cols w*64..w*64+63) ---------
  floatx4 acc[4][4];
  #pragma unroll
  for (int mt = 0; mt < 4; ++mt)
    #pragma unroll
    for (int nt = 0; nt < 4; ++nt) acc[mt][nt] = zero4();

  const ushort* wof = Wof + (size_t)w * 16 * 4 * 64 * 8;   // head slice
  for (int ks = 0; ks < 16; ++ks) {
    const int ce = ks * 32 + lg * 8;
    short8 b[4], a[4];
    #pragma unroll
    for (int nt = 0; nt < 4; ++nt)
      b[nt] = *(const short8*)(wof + (((size_t)ks * 4 + nt) * 64 + l) * 8);
    #pragma unroll
    for (int mt = 0; mt < 4; ++mt) {
      const int row = mt * 16 + lr;
      a[mt] = *(const short8*)(&sAO[row * 512 + (ce ^ ((row & 7) << 3))]);
    }
    #pragma unroll
    for (int mt = 0; mt < 4; ++mt)
      #pragma unroll
      for (int nt = 0; nt < 4; ++nt)
        acc[mt][nt] = MFMA16(a[mt], b[nt], acc[mt][nt]);
  }

  // epilogue (verbatim; head = w, edges m0..m0+63)
  #pragma unroll
  for (int nt = 0; nt < 4; ++nt) {
    const float bias = bo[w * 64 + nt * 16 + lr];
    #pragma unroll
    for (int mt = 0; mt < 4; ++mt)
      #pragma unroll
      for (int i = 0; i < 4; ++i)
        acc[mt][nt][i] = gelu_f(acc[mt][nt][i] + bias);
  }
  float lgA[4][4];
  #pragma unroll
  for (int mt = 0; mt < 4; ++mt)
    #pragma unroll
    for (int i = 0; i < 4; ++i) {
      float tA = acc[mt][2][i] + acc[mt][3][i];
      #pragma unroll
      for (int d2 = 1; d2 < 16; d2 <<= 1) tA += __shfl_xor(tA, d2);
      lgA[mt][i] = tA * (1.0f / 32.0f);
    }
  float eAv[4][4], iA[2];
  #pragma unroll
  for (int n = 0; n < 2; ++n) {
    float mx = -1e30f;
    #pragma unroll
    for (int m2 = 0; m2 < 2; ++m2)
      #pragma unroll
      for (int i = 0; i < 4; ++i) mx = fmaxf(mx, lgA[2 * n + m2][i]);
    mx = fmaxf(mx, __shfl_xor(mx, 16));
    mx = fmaxf(mx, __shfl_xor(mx, 32));
    float sA2 = 0.f;
    #pragma unroll
    for (int m2 = 0; m2 < 2; ++m2)
      #pragma unroll
      for (int i = 0; i < 4; ++i) {
        eAv[2 * n + m2][i] = expf(lgA[2 * n + m2][i] - mx);
        sA2 += eAv[2 * n + m2][i];
      }
    sA2 += __shfl_xor(sA2, 16);
    sA2 += __shfl_xor(sA2, 32);
    iA[n] = 1.0f / sA2;
  }
  #pragma unroll
  for (int mt = 0; mt < 4; ++mt)
    #pragma unroll
    for (int i = 0; i < 4; ++i) {
      const int r  = mt * 16 + lg * 4 + i;
      const int d1 = e[MEDGE + m0 + r];
      float* bp = out + (size_t)d1 * 256 + w * 32;
      const float aA = eAv[mt][i] * iA[mt >> 1];
      atomicAdd(bp + lr,      acc[mt][0][i] * aA);
      atomicAdd(bp + 16 + lr, acc[mt][1][i] * aA);
    }
}

// fp32 -> bf16 pre-convert
__global__ __launch_bounds__(256) void cvt_w(const float* __restrict__ src,
                                             ushort* __restrict__ dst, int n4)
{
  const int i = blockIdx.x * 256 + threadIdx.x;
  if (i < n4) {
    floatx4 v = *(const floatx4*)(src + (size_t)i * 4);
    short4v r;
    #pragma unroll
    for (int j = 0; j < 4; ++j) r[j] = (short)f2bf(v[j]);
    *(short4v*)(dst + (size_t)i * 4) = r;
  }
}

// ws layout: weights bf16 | xb bf16 | P12 f32 | Wof | chunk buffers
#define WS_WC 0
#define WS_WI (WS_WC + 512*KC)
#define WS_WO (WS_WI + 1536*DD)
#define WB_BYTES   2686976
#define XB_BYTES   4194304
#define P12_BYTES  33554432
#define WOF_BYTES  524288
#define CHUNK_OFF  (WB_BYTES + XB_BYTES + P12_BYTES + WOF_BYTES)

extern "C" void kernel_launch(void* const* d_in, const int* in_sizes, int n_in,
                              void* d_out, int out_size, void* d_ws, size_t ws_size,
                              hipStream_t stream)
{
  (void)in_sizes; (void)n_in;
  const float* x  = (const float*)d_in[0];
  const float* ea = (const float*)d_in[1];
  const int*   e  = (const int*)d_in[2];
  const float* Wc = (const float*)d_in[3];
  const float* bc = (const float*)d_in[4];
  const float* Wi = (const float*)d_in[5];
  const float* bi = (const float*)d_in[6];
  const float* Wo = (const float*)d_in[7];
  const float* bo = (const float*)d_in[8];

  ushort* wsb = (ushort*)d_ws;
  ushort* Wcb = wsb + WS_WC;
  ushort* Wib = wsb + WS_WI;
  ushort* Wob = wsb + WS_WO;
  ushort* xb  = (ushort*)((char*)d_ws + WB_BYTES);
  float*  P12 = (float*)((char*)d_ws + WB_BYTES + XB_BYTES);
  ushort* Wof = (ushort*)((char*)d_ws + WB_BYTES + XB_BYTES + P12_BYTES);

  cvt_w<<<dim3((512 * KC / 4 + 255) / 256), dim3(256), 0, stream>>>(Wc, Wcb, 512 * KC / 4);
  cvt_w<<<dim3((1536 * DD / 4 + 255) / 256), dim3(256), 0, stream>>>(Wi, Wib, 1536 * DD / 4);
  cvt_w<<<dim3((512 * DD / 4 + 255) / 256), dim3(256), 0, stream>>>(Wo, Wob, 512 * DD / 4);
  cvt_w<<<dim3((NNODE * DIN / 4 + 255) / 256), dim3(256), 0, stream>>>(x, xb, NNODE * DIN / 4);
  pack_wof<<<dim3(128), dim3(256), 0, stream>>>(Wob, Wof);

  k0_p12<<<dim3(64, 8), dim3(256), 0, stream>>>(xb, Wcb, P12);

  float* out = (float*)d_out;
  hipMemsetAsync(out, 0, (size_t)out_size * sizeof(float), stream);

  // chunk sizing: 4 buffers (ex, Qn, Kn, Vt), each C*32768 bytes
  size_t avail = ws_size > (size_t)CHUNK_OFF ? ws_size - (size_t)CHUNK_OFF : 0;
  long long Cll = (long long)(avail / 131072);
  int C = (int)(Cll > 8192 ? 8192 : Cll);
  C &= ~3;                      // multiple of 4 nodes (128-edge M-tiles)
  if (C < 4) C = 4;
  const size_t seg = (size_t)C * 32768;
  char* cbase = (char*)d_ws + CHUNK_OFF;
  ushort* exC = (ushort*)(cbase);
  ushort* Qn  = (ushort*)(cbase + seg);
  ushort* Kn  = (ushort*)(cbase + 2 * seg);
  ushort* Vt  = (ushort*)(cbase + 3 * seg);
  const int EC = C * 32;

  for (int n0 = 0; n0 < NNODE; n0 += C) {
    const int cc = (NNODE - n0 < C) ? (NNODE - n0) : C;
    k1_ex  <<<dim3(cc / 2), dim3(256), 0, stream>>>(ea, e, Wcb, bc, P12, exC, n0);
    k2a_qkv<<<dim3((cc / 4) * 12), dim3(256), 0, stream>>>(exC, Wib, bi, Qn, Kn, Vt, EC);
    k23_attn_out<<<dim3(cc / 2), dim3(512), 0, stream>>>(Qn, Kn, Vt, e, Wof, bo, out, EC, n0);
  }
}